// Round 10
// baseline (217.665 us; speedup 1.0000x reference)
//
#include <hip/hip_runtime.h>
#include <hip/hip_bf16.h>
#include <math.h>

#define DIM 768
#define NHEADS 16
#define HD 48
#define NTOK 1568
#define BATCH 4
#define ROWS (BATCH * NTOK)     // 6272
#define QKV_COLS (3 * DIM)      // 2304

typedef __attribute__((ext_vector_type(8))) short bf16x8;
typedef __attribute__((ext_vector_type(4))) float f32x4;

__device__ inline float b2f(ushort u) {
    union { float f; unsigned u; } v; v.u = ((unsigned)u) << 16; return v.f;
}
__device__ inline ushort f2b(float f) {
    union { float f; unsigned u; } v; v.f = f;
    unsigned r = v.u + 0x7fff + ((v.u >> 16) & 1);   // round-to-nearest-even
    return (ushort)(r >> 16);
}

// async global->LDS, 16B per lane; lds dest is wave-uniform base (+lane*16 by HW)
__device__ inline void gl16(const void* g, void* l) {
    __builtin_amdgcn_global_load_lds(
        (const __attribute__((address_space(1))) unsigned int*)g,
        (__attribute__((address_space(3))) unsigned int*)l, 16, 0, 0);
}

// ---------------- cast fp32 -> bf16 (vectorized) -----------------------------
__global__ void cast_f32_bf16(const float* __restrict__ in, ushort* __restrict__ out, int n4) {
    int i = blockIdx.x * blockDim.x + threadIdx.x;
    if (i >= n4) return;
    float4 v = ((const float4*)in)[i];
    ushort4 o;
    o.x = f2b(v.x); o.y = f2b(v.y); o.z = f2b(v.z); o.w = f2b(v.w);
    ((ushort4*)out)[i] = o;
}

// ---------------- transpose-cast: in[R][C] f32 -> out[C][R] bf16 -------------
__global__ void transpose_cast(const float* __restrict__ in, ushort* __restrict__ out,
                               int R, int C) {
    __shared__ ushort tile[32][33];
    int tx = threadIdx.x, ty = threadIdx.y;
    int c0 = blockIdx.x * 32, r0 = blockIdx.y * 32;
#pragma unroll
    for (int k = 0; k < 4; ++k)
        tile[ty + 8 * k][tx] = f2b(in[(size_t)(r0 + ty + 8 * k) * C + c0 + tx]);
    __syncthreads();
#pragma unroll
    for (int k = 0; k < 4; ++k)
        out[(size_t)(c0 + ty + 8 * k) * R + r0 + tx] = tile[tx][ty + 8 * k];
}

// ------- split-transpose W_proj [768][768] f32 -> out[768][2304] = [wh|wh|wl]
__global__ void split_transpose_wp(const float* __restrict__ in, ushort* __restrict__ out) {
    __shared__ float tile[32][33];
    int tx = threadIdx.x, ty = threadIdx.y;
    int c0 = blockIdx.x * 32, r0 = blockIdx.y * 32;   // r = k, c = n
#pragma unroll
    for (int k = 0; k < 4; ++k)
        tile[ty + 8 * k][tx] = in[(size_t)(r0 + ty + 8 * k) * DIM + c0 + tx];
    __syncthreads();
#pragma unroll
    for (int k = 0; k < 4; ++k) {
        float w = tile[tx][ty + 8 * k];
        ushort hi = f2b(w);
        ushort lo = f2b(w - b2f(hi));
        size_t base = (size_t)(c0 + ty + 8 * k) * QKV_COLS + r0 + tx;
        out[base] = hi; out[base + DIM] = hi; out[base + 2 * DIM] = lo;
    }
}

// ------- transpose V slice of qkv: vt[b][c][n] = qkv[b][n][1536+c], c in [0,768)
__global__ void transpose_v(const ushort* __restrict__ qkv, ushort* __restrict__ vt) {
    __shared__ ushort tile[32][33];
    int tx = threadIdx.x, ty = threadIdx.y;   // 32x8
    int c0 = blockIdx.x * 32, n0 = blockIdx.y * 32, b = blockIdx.z;
    const ushort* src = qkv + (size_t)b * NTOK * QKV_COLS + 2 * DIM;
#pragma unroll
    for (int k = 0; k < 4; ++k)
        tile[ty + 8 * k][tx] = src[(size_t)(n0 + ty + 8 * k) * QKV_COLS + c0 + tx];
    __syncthreads();
    ushort* dst = vt + (size_t)b * DIM * NTOK;
#pragma unroll
    for (int k = 0; k < 4; ++k)
        dst[(size_t)(c0 + ty + 8 * k) * NTOK + n0 + tx] = tile[tx][ty + 8 * k];
}

// ---------------- bf16 MFMA GEMM: C[M][N] = A[M][K] * Bt[N][K]^T -------------
// global_load_lds staging, linear LDS [row][64] with both-sides XOR swizzle.
#define GBM 128
#define GBN 128
#define GBK 64

__global__ __launch_bounds__(256) void gemm_bf16(
    const ushort* __restrict__ A, const ushort* __restrict__ Bt,
    float* __restrict__ Cf, ushort* __restrict__ Cb,
    const float* __restrict__ bias, int M, int N, int K) {
    __shared__ ushort sA[GBM * 64];
    __shared__ ushort sB[GBN * 64];
    const int tid = threadIdx.x;
    const int wid = tid >> 6, lane = tid & 63;
    const int wm = wid >> 1, wn = wid & 1;          // 2x2 wave grid, 64x64 per wave
    const int m0 = blockIdx.y * GBM, n0 = blockIdx.x * GBN;
    const int lr = lane & 15, g = lane >> 4;

    f32x4 acc[4][4] = {};
    for (int k0 = 0; k0 < K; k0 += GBK) {
        __syncthreads();
#pragma unroll
        for (int i = 0; i < 4; ++i) {
            int c = tid + 256 * i;                   // 1024 chunks of 16B
            int row = c >> 3;
            int ch = (c & 7) ^ (row & 7);            // source pre-swizzle
            int ub = (c & ~63) * 8;                  // wave-uniform dest (ushort idx)
            gl16(&A[(size_t)(m0 + row) * K + k0 + ch * 8], &sA[ub]);
            gl16(&Bt[(size_t)(n0 + row) * K + k0 + ch * 8], &sB[ub]);
        }
        __syncthreads();                             // drains vmcnt: tiles ready
#pragma unroll
        for (int k2 = 0; k2 < GBK; k2 += 32) {
            bf16x8 af[4], bg[4];
#pragma unroll
            for (int f = 0; f < 4; ++f) {
                int ra = wm * 64 + f * 16 + lr;
                int ba = (ra * 128 + k2 * 2 + g * 16) ^ ((ra & 7) << 4);
                af[f] = *(const bf16x8*)((const char*)sA + ba);
                int rb = wn * 64 + f * 16 + lr;
                int bb = (rb * 128 + k2 * 2 + g * 16) ^ ((rb & 7) << 4);
                bg[f] = *(const bf16x8*)((const char*)sB + bb);
            }
#pragma unroll
            for (int mi = 0; mi < 4; ++mi)
#pragma unroll
                for (int ni = 0; ni < 4; ++ni)
                    acc[mi][ni] = __builtin_amdgcn_mfma_f32_16x16x32_bf16(
                        af[mi], bg[ni], acc[mi][ni], 0, 0, 0);
        }
    }
    const int cr = (lane >> 4) * 4;
#pragma unroll
    for (int mi = 0; mi < 4; ++mi)
#pragma unroll
        for (int ni = 0; ni < 4; ++ni) {
            int col = n0 + wn * 64 + ni * 16 + lr;
#pragma unroll
            for (int j = 0; j < 4; ++j) {
                int row = m0 + wm * 64 + mi * 16 + cr + j;
                float v = acc[mi][ni][j];
                if (Cf) {
                    if (bias) v += bias[col];
                    Cf[(size_t)row * N + col] = v;
                } else {
                    Cb[(size_t)row * N + col] = f2b(v);
                }
            }
        }
}

// ---------------- RoPE 3D, vectorized: thread = (b,n,h,axis), 8 pairs --------
__global__ void rope_bf16(ushort* __restrict__ qkv, const int* __restrict__ pos) {
    int idx = blockIdx.x * blockDim.x + threadIdx.x;
    const int total = BATCH * NTOK * NHEADS * 3;   // 301056
    if (idx >= total) return;
    int axis = idx % 3; int t = idx / 3;
    int h = t & 15; t >>= 4;
    int n = t % NTOK; int b = t / NTOK;

    float p = (float)pos[n * 3 + axis];
    size_t base = ((size_t)b * NTOK + n) * QKV_COLS + h * HD + axis * 16;

    bf16x8 qlo = *(bf16x8*)&qkv[base],       qhi = *(bf16x8*)&qkv[base + 8];
    bf16x8 klo = *(bf16x8*)&qkv[base + DIM], khi = *(bf16x8*)&qkv[base + DIM + 8];

    const float RINV = 0.31622776601683794f;   // 10000^(-1/8)
    float fj = 1.0f;
#pragma unroll
    for (int j = 0; j < 8; ++j) {
        float s, c; __sincosf(p * fj, &s, &c); fj *= RINV;
        float q1 = b2f((ushort)qlo[j]), q2 = b2f((ushort)qhi[j]);
        qlo[j] = (short)f2b(q1 * c - q2 * s);
        qhi[j] = (short)f2b(q2 * c + q1 * s);
        float k1 = b2f((ushort)klo[j]), k2 = b2f((ushort)khi[j]);
        klo[j] = (short)f2b(k1 * c - k2 * s);
        khi[j] = (short)f2b(k2 * c + k1 * s);
    }
    *(bf16x8*)&qkv[base] = qlo;       *(bf16x8*)&qkv[base + 8] = qhi;
    *(bf16x8*)&qkv[base + DIM] = klo; *(bf16x8*)&qkv[base + DIM + 8] = khi;
}

// ---------------- MFMA flash attention ---------------------------------------
// Grid: (64 bh, 25 q-tiles) — bh%8 = XCD -> K/V L2-resident per XCD.
// QBLK=64 (wave owns 16 q-rows) -> 1600 blocks = 6.25/CU for latency hiding.
// Double-buffered K/V via global_load_lds, counted vmcnt(2), raw barriers.
// Fixed-offset exp2 softmax; -32 folded into MFMA C-init; l via ones-row
// (V^T row 48 = 1.0) as a 4th PV MFMA -> zero softmax-reduction VALU.
#define QBLK 64
#define KVB 32
#define NT (NTOK / KVB)   // 49
#define PP 40             // sP pitch

__global__ __launch_bounds__(256) void attn_mfma(const ushort* __restrict__ qkv,
                                                 const ushort* __restrict__ vt,
                                                 ushort* __restrict__ asplit) {
    __shared__ ushort sK2[2][KVB * 64];   // [32][64] linear, 8 KB
    __shared__ ushort sV2[2][64 * 32];    // [64][32]: rows 0..47 V^T, 48 = ones
    __shared__ ushort sP[4][16 * PP];     // 5 KB
    const int tid = threadIdx.x, w = tid >> 6, lane = tid & 63;
    const int b = blockIdx.x >> 4, h = blockIdx.x & 15;
    const int q0 = blockIdx.y * QBLK;
    const size_t bbase = (size_t)b * NTOK * QKV_COLS;
    const size_t vbase = ((size_t)b * DIM + h * HD) * NTOK;
    const int lr = lane & 15, g = lane >> 4, lk = g << 3;
    const float qs = 0.14433756729740643f * 1.4426950408889634f;  // 1/sqrt(48)*log2e
    const float M2 = 32.0f;   // fixed exp2-domain offset (folded into C-init)

    // ones-row for l-accumulation (row 48 of both V buffers); rows 49..63 unused
    if (tid < 32) {
        sV2[0][48 * 32 + tid] = 0x3F80;
        sV2[1][48 * 32 + tid] = 0x3F80;
    }
    asm volatile("s_waitcnt lgkmcnt(0)" ::: "memory");

    // Q direct to registers, scaled by qs; cols >= 48 zero (nulls K garbage)
    bf16x8 aq[2];
    {
        int qr = q0 + w * 16 + lr;
        if (qr >= NTOK) qr = NTOK - 1;
        const ushort* qp = &qkv[bbase + (size_t)qr * QKV_COLS + h * HD];
        bf16x8 r0 = *(const bf16x8*)&qp[lk];
        bf16x8 r1 = {};
        if (g < 2) r1 = *(const bf16x8*)&qp[32 + lk];
#pragma unroll
        for (int e = 0; e < 8; ++e) {
            r0[e] = (short)f2b(b2f((ushort)r0[e]) * qs);
            r1[e] = (short)f2b(b2f((ushort)r1[e]) * qs);
        }
        aq[0] = r0; aq[1] = r1;
    }

    // stage K (256 chunks) + V (192 chunks) for tile kv0 into buffer buf
    auto STAGE = [&](int buf, int kv0) {
        {   // K: chunk c = tid; row = c>>3; source chunk swizzled
            int c = tid, row = c >> 3;
            int ch = (c & 7) ^ (row & 7);
            gl16(&qkv[bbase + (size_t)(kv0 + row) * QKV_COLS + DIM + h * HD + ch * 8],
                 &sK2[buf][(c & ~63) * 8]);
        }
        if (lane < 48) {   // V: wave w stages chunks w*48..w*48+47 (rows 0..47)
            int c = w * 48 + lane, d = c >> 2;
            int cc = (c & 3) ^ ((d >> 1) & 3);
            gl16(&vt[vbase + (size_t)d * NTOK + kv0 + cc * 8],
                 &sV2[buf][w * 384]);
        }
    };

    f32x4 o[4] = {};   // o[0..2] = output d 0..47; o[3]: (g0,j0) = l

    STAGE(0, 0);
    for (int t = 0; t < NT; ++t) {
        const int cur = t & 1;
        if (t + 1 < NT) {
            STAGE(cur ^ 1, (t + 1) * KVB);
            asm volatile("s_waitcnt vmcnt(2)" ::: "memory");  // tile t's 2 loads done
        } else {
            asm volatile("s_waitcnt vmcnt(0)" ::: "memory");
        }
        __builtin_amdgcn_s_barrier();

        // S^T = K Q^T - 32: lane: q = lr, keys = f*16 + 4g + j
        bf16x8 bk[2][2];
#pragma unroll
        for (int f = 0; f < 2; ++f)
#pragma unroll
            for (int ks = 0; ks < 2; ++ks) {
                int row = f * 16 + lr;
                int byt = (row * 128 + ks * 64 + g * 16) ^ ((lr & 7) << 4);
                bk[f][ks] = *(const bf16x8*)((const char*)sK2[cur] + byt);
            }
        f32x4 sacc[2] = {{-M2, -M2, -M2, -M2}, {-M2, -M2, -M2, -M2}};
#pragma unroll
        for (int f = 0; f < 2; ++f) {
            sacc[f] = __builtin_amdgcn_mfma_f32_16x16x32_bf16(bk[f][0], aq[0], sacc[f], 0, 0, 0);
            sacc[f] = __builtin_amdgcn_mfma_f32_16x16x32_bf16(bk[f][1], aq[1], sacc[f], 0, 0, 0);
        }

        // p = 2^(s2-32); pack adjacent-key pairs -> b64 stores to sP[q][key]
#pragma unroll
        for (int f = 0; f < 2; ++f) {
            float p[4];
#pragma unroll
            for (int j = 0; j < 4; ++j) {
                float pv;
                asm("v_exp_f32 %0, %1" : "=v"(pv) : "v"(sacc[f][j]));
                p[j] = pv;
            }
            uint u0, u1;
            asm("v_cvt_pk_bf16_f32 %0, %1, %2" : "=v"(u0) : "v"(p[0]), "v"(p[1]));
            asm("v_cvt_pk_bf16_f32 %0, %1, %2" : "=v"(u1) : "v"(p[2]), "v"(p[3]));
            uint2 uu; uu.x = u0; uu.y = u1;
            *(uint2*)&sP[w][lr * PP + f * 16 + 4 * g] = uu;
        }

        // PV (swapped): o^T = mfma(V^T, P): lane: q = lr, d = 16nf + 4g + j
        // nf=3 row 48 = ones -> accumulates l into o[3] (g=0,j=0)
        bf16x8 bv[4];
#pragma unroll
        for (int nf = 0; nf < 4; ++nf) {
            int row = nf * 16 + lr;
            int byt = (row * 64 + g * 16) ^ (((lr >> 1) & 3) << 4);
            bv[nf] = *(const bf16x8*)((const char*)sV2[cur] + byt);
        }
        bf16x8 pa = *(const bf16x8*)&sP[w][lr * PP + lk];
#pragma unroll
        for (int nf = 0; nf < 4; ++nf)
            o[nf] = __builtin_amdgcn_mfma_f32_16x16x32_bf16(bv[nf], pa, o[nf], 0, 0, 0);

        asm volatile("s_waitcnt lgkmcnt(0)" ::: "memory");  // LDS ops retired
        __builtin_amdgcn_s_barrier();                       // buffer-reuse fence
    }

    // l lives in o[3][0] of lanes g==0 (lane == lr): broadcast to the q-group
    float lv = __shfl(o[3][0], lr, 64);

    // epilogue: lane q = q0 + w*16 + lr; d = 16nf + 4g + j (contiguous)
    int qr = q0 + w * 16 + lr;
    if (qr < NTOK) {
        float inv = 1.f / lv;
        size_t rbse = ((size_t)b * NTOK + qr) * QKV_COLS;
#pragma unroll
        for (int nf = 0; nf < 3; ++nf) {
            ushort4 hi4, lo4;
#pragma unroll
            for (int j = 0; j < 4; ++j) {
                float v = o[nf][j] * inv;
                ushort hv = f2b(v);
                ((ushort*)&hi4)[j] = hv;
                ((ushort*)&lo4)[j] = f2b(v - b2f(hv));
            }
            int c = h * HD + nf * 16 + 4 * g;
            *(ushort4*)&asplit[rbse + c] = hi4;
            *(ushort4*)&asplit[rbse + DIM + c] = lo4;
            *(ushort4*)&asplit[rbse + 2 * DIM + c] = hi4;
        }
    }
}

// ---------------- launch ------------------------------------------------------
extern "C" void kernel_launch(void* const* d_in, const int* in_sizes, int n_in,
                              void* d_out, int out_size, void* d_ws, size_t ws_size,
                              hipStream_t stream) {
    const float* x   = (const float*)d_in[0];
    const int*   pos = (const int*)d_in[1];
    const float* Wq  = (const float*)d_in[2];
    const float* Wp  = (const float*)d_in[3];
    const float* bp  = (const float*)d_in[4];
    float* out = (float*)d_out;

    ushort* ws     = (ushort*)d_ws;
    ushort* x_bf   = ws;                                    // 6272*768 (later reused as vt)
    ushort* WqT    = x_bf + (size_t)ROWS * DIM;             // 2304*768
    ushort* WpT3   = WqT + (size_t)QKV_COLS * DIM;          // 768*2304
    ushort* qkv_bf = WpT3 + (size_t)DIM * QKV_COLS;         // 6272*2304
    ushort* asplit = qkv_bf + (size_t)ROWS * QKV_COLS;      // 6272*2304
    ushort* vt     = x_bf;   // alias: x_bf dead after gemm1; 4*768*1568 == 6272*768

    cast_f32_bf16<<<(ROWS * DIM / 4 + 255) / 256, 256, 0, stream>>>(x, x_bf, ROWS * DIM / 4);
    transpose_cast<<<dim3(QKV_COLS / 32, DIM / 32), dim3(32, 8), 0, stream>>>(Wq, WqT, DIM, QKV_COLS);
    split_transpose_wp<<<dim3(DIM / 32, DIM / 32), dim3(32, 8), 0, stream>>>(Wp, WpT3);

    // qkv = x @ W_qkv  (bf16 out)
    gemm_bf16<<<dim3(QKV_COLS / GBN, ROWS / GBM), 256, 0, stream>>>(
        x_bf, WqT, nullptr, qkv_bf, nullptr, ROWS, QKV_COLS, DIM);

    // vt[b][c][n] = V^T (overwrites x_bf, which is dead now)
    transpose_v<<<dim3(DIM / 32, NTOK / 32, BATCH), dim3(32, 8), 0, stream>>>(qkv_bf, vt);

    rope_bf16<<<(BATCH * NTOK * NHEADS * 3 + 255) / 256, 256, 0, stream>>>(qkv_bf, pos);

    attn_mfma<<<dim3(BATCH * NHEADS, (NTOK + QBLK - 1) / QBLK), 256, 0, stream>>>(qkv_bf, vt, asplit);

    // out = asplit @ WpT3^T + b  (split-bf16, K=2304, f32 out)
    gemm_bf16<<<dim3(DIM / GBN, ROWS / GBM), 256, 0, stream>>>(
        asplit, WpT3, out, nullptr, bp, ROWS, DIM, QKV_COLS);
}

// Round 11
// 200.878 us; speedup vs baseline: 1.0836x; 1.0836x over previous
//
#include <hip/hip_runtime.h>
#include <hip/hip_bf16.h>
#include <math.h>

#define DIM 768
#define NHEADS 16
#define HD 48
#define NTOK 1568
#define BATCH 4
#define ROWS (BATCH * NTOK)     // 6272
#define QKV_COLS (3 * DIM)      // 2304

typedef __attribute__((ext_vector_type(8))) short bf16x8;
typedef __attribute__((ext_vector_type(4))) float f32x4;

__device__ inline float b2f(ushort u) {
    union { float f; unsigned u; } v; v.u = ((unsigned)u) << 16; return v.f;
}
__device__ inline ushort f2b(float f) {
    union { float f; unsigned u; } v; v.f = f;
    unsigned r = v.u + 0x7fff + ((v.u >> 16) & 1);   // round-to-nearest-even
    return (ushort)(r >> 16);
}

// async global->LDS, 16B per lane; lds dest is wave-uniform base (+lane*16 by HW)
__device__ inline void gl16(const void* g, void* l) {
    __builtin_amdgcn_global_load_lds(
        (const __attribute__((address_space(1))) unsigned int*)g,
        (__attribute__((address_space(3))) unsigned int*)l, 16, 0, 0);
}

// ---------------- cast fp32 -> bf16 (vectorized) -----------------------------
__global__ void cast_f32_bf16(const float* __restrict__ in, ushort* __restrict__ out, int n4) {
    int i = blockIdx.x * blockDim.x + threadIdx.x;
    if (i >= n4) return;
    float4 v = ((const float4*)in)[i];
    ushort4 o;
    o.x = f2b(v.x); o.y = f2b(v.y); o.z = f2b(v.z); o.w = f2b(v.w);
    ((ushort4*)out)[i] = o;
}

// ---------------- transpose-cast: in[R][C] f32 -> out[C][R] bf16 -------------
__global__ void transpose_cast(const float* __restrict__ in, ushort* __restrict__ out,
                               int R, int C) {
    __shared__ ushort tile[32][33];
    int tx = threadIdx.x, ty = threadIdx.y;
    int c0 = blockIdx.x * 32, r0 = blockIdx.y * 32;
#pragma unroll
    for (int k = 0; k < 4; ++k)
        tile[ty + 8 * k][tx] = f2b(in[(size_t)(r0 + ty + 8 * k) * C + c0 + tx]);
    __syncthreads();
#pragma unroll
    for (int k = 0; k < 4; ++k)
        out[(size_t)(c0 + ty + 8 * k) * R + r0 + tx] = tile[tx][ty + 8 * k];
}

// ------- split-transpose W_proj [768][768] f32 -> out[768][2304] = [wh|wh|wl]
__global__ void split_transpose_wp(const float* __restrict__ in, ushort* __restrict__ out) {
    __shared__ float tile[32][33];
    int tx = threadIdx.x, ty = threadIdx.y;
    int c0 = blockIdx.x * 32, r0 = blockIdx.y * 32;   // r = k, c = n
#pragma unroll
    for (int k = 0; k < 4; ++k)
        tile[ty + 8 * k][tx] = in[(size_t)(r0 + ty + 8 * k) * DIM + c0 + tx];
    __syncthreads();
#pragma unroll
    for (int k = 0; k < 4; ++k) {
        float w = tile[tx][ty + 8 * k];
        ushort hi = f2b(w);
        ushort lo = f2b(w - b2f(hi));
        size_t base = (size_t)(c0 + ty + 8 * k) * QKV_COLS + r0 + tx;
        out[base] = hi; out[base + DIM] = hi; out[base + 2 * DIM] = lo;
    }
}

// ------- transpose V slice of qkv: vt[b][c][n] = qkv[b][n][1536+c], c in [0,768)
__global__ void transpose_v(const ushort* __restrict__ qkv, ushort* __restrict__ vt) {
    __shared__ ushort tile[32][33];
    int tx = threadIdx.x, ty = threadIdx.y;   // 32x8
    int c0 = blockIdx.x * 32, n0 = blockIdx.y * 32, b = blockIdx.z;
    const ushort* src = qkv + (size_t)b * NTOK * QKV_COLS + 2 * DIM;
#pragma unroll
    for (int k = 0; k < 4; ++k)
        tile[ty + 8 * k][tx] = src[(size_t)(n0 + ty + 8 * k) * QKV_COLS + c0 + tx];
    __syncthreads();
    ushort* dst = vt + (size_t)b * DIM * NTOK;
#pragma unroll
    for (int k = 0; k < 4; ++k)
        dst[(size_t)(c0 + ty + 8 * k) * NTOK + n0 + tx] = tile[tx][ty + 8 * k];
}

// ---------------- bf16 MFMA GEMM: C[M][N] = A[M][K] * Bt[N][K]^T -------------
#define GBM 128
#define GBN 128
#define GBK 64

__global__ __launch_bounds__(256) void gemm_bf16(
    const ushort* __restrict__ A, const ushort* __restrict__ Bt,
    float* __restrict__ Cf, ushort* __restrict__ Cb,
    const float* __restrict__ bias, int M, int N, int K) {
    __shared__ ushort sA[GBM * 64];
    __shared__ ushort sB[GBN * 64];
    const int tid = threadIdx.x;
    const int wid = tid >> 6, lane = tid & 63;
    const int wm = wid >> 1, wn = wid & 1;          // 2x2 wave grid, 64x64 per wave
    const int m0 = blockIdx.y * GBM, n0 = blockIdx.x * GBN;
    const int lr = lane & 15, g = lane >> 4;

    f32x4 acc[4][4] = {};
    for (int k0 = 0; k0 < K; k0 += GBK) {
        __syncthreads();
#pragma unroll
        for (int i = 0; i < 4; ++i) {
            int c = tid + 256 * i;                   // 1024 chunks of 16B
            int row = c >> 3;
            int ch = (c & 7) ^ (row & 7);            // source pre-swizzle
            int ub = (c & ~63) * 8;                  // wave-uniform dest (ushort idx)
            gl16(&A[(size_t)(m0 + row) * K + k0 + ch * 8], &sA[ub]);
            gl16(&Bt[(size_t)(n0 + row) * K + k0 + ch * 8], &sB[ub]);
        }
        __syncthreads();                             // drains vmcnt: tiles ready
#pragma unroll
        for (int k2 = 0; k2 < GBK; k2 += 32) {
            bf16x8 af[4], bg[4];
#pragma unroll
            for (int f = 0; f < 4; ++f) {
                int ra = wm * 64 + f * 16 + lr;
                int ba = (ra * 128 + k2 * 2 + g * 16) ^ ((ra & 7) << 4);
                af[f] = *(const bf16x8*)((const char*)sA + ba);
                int rb = wn * 64 + f * 16 + lr;
                int bb = (rb * 128 + k2 * 2 + g * 16) ^ ((rb & 7) << 4);
                bg[f] = *(const bf16x8*)((const char*)sB + bb);
            }
#pragma unroll
            for (int mi = 0; mi < 4; ++mi)
#pragma unroll
                for (int ni = 0; ni < 4; ++ni)
                    acc[mi][ni] = __builtin_amdgcn_mfma_f32_16x16x32_bf16(
                        af[mi], bg[ni], acc[mi][ni], 0, 0, 0);
        }
    }
    const int cr = (lane >> 4) * 4;
#pragma unroll
    for (int mi = 0; mi < 4; ++mi)
#pragma unroll
        for (int ni = 0; ni < 4; ++ni) {
            int col = n0 + wn * 64 + ni * 16 + lr;
#pragma unroll
            for (int j = 0; j < 4; ++j) {
                int row = m0 + wm * 64 + mi * 16 + cr + j;
                float v = acc[mi][ni][j];
                if (Cf) {
                    if (bias) v += bias[col];
                    Cf[(size_t)row * N + col] = v;
                } else {
                    Cb[(size_t)row * N + col] = f2b(v);
                }
            }
        }
}

// ---------------- RoPE 3D, vectorized: thread = (b,n,h,axis), 8 pairs --------
__global__ void rope_bf16(ushort* __restrict__ qkv, const int* __restrict__ pos) {
    int idx = blockIdx.x * blockDim.x + threadIdx.x;
    const int total = BATCH * NTOK * NHEADS * 3;   // 301056
    if (idx >= total) return;
    int axis = idx % 3; int t = idx / 3;
    int h = t & 15; t >>= 4;
    int n = t % NTOK; int b = t / NTOK;

    float p = (float)pos[n * 3 + axis];
    size_t base = ((size_t)b * NTOK + n) * QKV_COLS + h * HD + axis * 16;

    bf16x8 qlo = *(bf16x8*)&qkv[base],       qhi = *(bf16x8*)&qkv[base + 8];
    bf16x8 klo = *(bf16x8*)&qkv[base + DIM], khi = *(bf16x8*)&qkv[base + DIM + 8];

    const float RINV = 0.31622776601683794f;   // 10000^(-1/8)
    float fj = 1.0f;
#pragma unroll
    for (int j = 0; j < 8; ++j) {
        float s, c; __sincosf(p * fj, &s, &c); fj *= RINV;
        float q1 = b2f((ushort)qlo[j]), q2 = b2f((ushort)qhi[j]);
        qlo[j] = (short)f2b(q1 * c - q2 * s);
        qhi[j] = (short)f2b(q2 * c + q1 * s);
        float k1 = b2f((ushort)klo[j]), k2 = b2f((ushort)khi[j]);
        klo[j] = (short)f2b(k1 * c - k2 * s);
        khi[j] = (short)f2b(k2 * c + k1 * s);
    }
    *(bf16x8*)&qkv[base] = qlo;       *(bf16x8*)&qkv[base + 8] = qhi;
    *(bf16x8*)&qkv[base + DIM] = klo; *(bf16x8*)&qkv[base + DIM + 8] = khi;
}

// ---------------- MFMA flash attention ---------------------------------------
// Grid: (64 bh, 13 q-tiles), bh%8 = XCD. QBLK=128 (wave owns 32 q-rows).
// TRIPLE-buffered K/V via global_load_lds, depth-2 pipeline, ONE barrier/tile:
//   iter t: vmcnt(2) [own stage-t landed] -> barrier [tile ready + t-1 reads
//   consumed pre-barrier via compiler lgkmcnt] -> issue STAGE(t+2) -> compute.
// Fixed-offset exp2 softmax; -32 in MFMA C-init; l via ones-row (V^T row 48).
#define QBLK 128
#define KVB 32
#define NT (NTOK / KVB)   // 49
#define PP 40             // sP pitch

__global__ __launch_bounds__(256) void attn_mfma(const ushort* __restrict__ qkv,
                                                 const ushort* __restrict__ vt,
                                                 ushort* __restrict__ asplit) {
    __shared__ ushort sK3[3][KVB * 64];   // [32][64] linear, 12 KB
    __shared__ ushort sV3[3][64 * 32];    // rows 0..47 V^T, 48 = ones; 12 KB
    __shared__ ushort sP[4][32 * PP];     // 10 KB
    const int tid = threadIdx.x, w = tid >> 6, lane = tid & 63;
    const int b = blockIdx.x >> 4, h = blockIdx.x & 15;
    const int q0 = blockIdx.y * QBLK;
    const size_t bbase = (size_t)b * NTOK * QKV_COLS;
    const size_t vbase = ((size_t)b * DIM + h * HD) * NTOK;
    const int lr = lane & 15, g = lane >> 4, lk = g << 3;
    const float qs = 0.14433756729740643f * 1.4426950408889634f;  // 1/sqrt(48)*log2e
    const float M2 = 32.0f;   // fixed exp2-domain offset (folded into C-init)

    // ones-row for l-accumulation (row 48 of all 3 V buffers)
    if (tid < 32) {
        sV3[0][48 * 32 + tid] = 0x3F80;
        sV3[1][48 * 32 + tid] = 0x3F80;
        sV3[2][48 * 32 + tid] = 0x3F80;
    }
    asm volatile("s_waitcnt lgkmcnt(0)" ::: "memory");

    // Q direct to registers, scaled by qs; cols >= 48 zero (nulls K garbage)
    bf16x8 aq[2][2];
#pragma unroll
    for (int rb = 0; rb < 2; ++rb) {
        int qr = q0 + w * 32 + rb * 16 + lr;
        if (qr >= NTOK) qr = NTOK - 1;
        const ushort* qp = &qkv[bbase + (size_t)qr * QKV_COLS + h * HD];
        bf16x8 r0 = *(const bf16x8*)&qp[lk];
        bf16x8 r1 = {};
        if (g < 2) r1 = *(const bf16x8*)&qp[32 + lk];
#pragma unroll
        for (int e = 0; e < 8; ++e) {
            r0[e] = (short)f2b(b2f((ushort)r0[e]) * qs);
            r1[e] = (short)f2b(b2f((ushort)r1[e]) * qs);
        }
        aq[rb][0] = r0; aq[rb][1] = r1;
    }

    // stage K (256 chunks) + V (192 chunks) for tile kv0 into buffer buf
    // = 2 vmem instructions per wave
    auto STAGE = [&](int buf, int kv0) {
        {   // K: chunk c = tid; row = c>>3; source chunk swizzled
            int c = tid, row = c >> 3;
            int ch = (c & 7) ^ (row & 7);
            gl16(&qkv[bbase + (size_t)(kv0 + row) * QKV_COLS + DIM + h * HD + ch * 8],
                 &sK3[buf][(c & ~63) * 8]);
        }
        if (lane < 48) {   // V: wave w stages chunks w*48..w*48+47 (rows 0..47)
            int c = w * 48 + lane, d = c >> 2;
            int cc = (c & 3) ^ ((d >> 1) & 3);
            gl16(&vt[vbase + (size_t)d * NTOK + kv0 + cc * 8],
                 &sV3[buf][w * 384]);
        }
    };

    f32x4 o[2][4] = {};   // per rb: d 0..47 in [0..2]; [3][0] (g=0) = l

    STAGE(0, 0);
    STAGE(1, KVB);
    for (int t = 0; t < NT; ++t) {
        const int cur = t % 3;
        if (t + 1 < NT) asm volatile("s_waitcnt vmcnt(2)" ::: "memory");
        else            asm volatile("s_waitcnt vmcnt(0)" ::: "memory");
        __builtin_amdgcn_s_barrier();
        if (t + 2 < NT) STAGE((t + 2) % 3, (t + 2) * KVB);

        // S^T = K Q^T - 32: lane: q = rb*16+lr, keys = f*16 + 4g + j
        bf16x8 bk[2][2];
#pragma unroll
        for (int f = 0; f < 2; ++f)
#pragma unroll
            for (int ks = 0; ks < 2; ++ks) {
                int row = f * 16 + lr;
                int byt = (row * 128 + ks * 64 + g * 16) ^ ((lr & 7) << 4);
                bk[f][ks] = *(const bf16x8*)((const char*)sK3[cur] + byt);
            }
        f32x4 sacc[2][2] = {{{-M2, -M2, -M2, -M2}, {-M2, -M2, -M2, -M2}},
                            {{-M2, -M2, -M2, -M2}, {-M2, -M2, -M2, -M2}}};
        __builtin_amdgcn_s_setprio(1);
#pragma unroll
        for (int rb = 0; rb < 2; ++rb)
#pragma unroll
            for (int f = 0; f < 2; ++f) {
                sacc[rb][f] = __builtin_amdgcn_mfma_f32_16x16x32_bf16(bk[f][0], aq[rb][0], sacc[rb][f], 0, 0, 0);
                sacc[rb][f] = __builtin_amdgcn_mfma_f32_16x16x32_bf16(bk[f][1], aq[rb][1], sacc[rb][f], 0, 0, 0);
            }
        __builtin_amdgcn_s_setprio(0);

        // p = 2^(s2-32); pack adjacent-key pairs -> b64 stores to sP[q][key]
#pragma unroll
        for (int rb = 0; rb < 2; ++rb)
#pragma unroll
            for (int f = 0; f < 2; ++f) {
                float p[4];
#pragma unroll
                for (int j = 0; j < 4; ++j) {
                    float pv;
                    asm("v_exp_f32 %0, %1" : "=v"(pv) : "v"(sacc[rb][f][j]));
                    p[j] = pv;
                }
                uint u0, u1;
                asm("v_cvt_pk_bf16_f32 %0, %1, %2" : "=v"(u0) : "v"(p[0]), "v"(p[1]));
                asm("v_cvt_pk_bf16_f32 %0, %1, %2" : "=v"(u1) : "v"(p[2]), "v"(p[3]));
                uint2 uu; uu.x = u0; uu.y = u1;
                *(uint2*)&sP[w][(rb * 16 + lr) * PP + f * 16 + 4 * g] = uu;
            }

        // PV (swapped): o^T = mfma(V^T, P): lane: q = lr, d = 16nf + 4g + j
        // nf=3 row 48 = ones -> accumulates l into o[rb][3] (g=0,j=0)
        bf16x8 bv[4];
#pragma unroll
        for (int nf = 0; nf < 4; ++nf) {
            int row = nf * 16 + lr;
            int byt = (row * 64 + g * 16) ^ (((lr >> 1) & 3) << 4);
            bv[nf] = *(const bf16x8*)((const char*)sV3[cur] + byt);
        }
        __builtin_amdgcn_s_setprio(1);
#pragma unroll
        for (int rb = 0; rb < 2; ++rb) {
            bf16x8 pa = *(const bf16x8*)&sP[w][(rb * 16 + lr) * PP + lk];
#pragma unroll
            for (int nf = 0; nf < 4; ++nf)
                o[rb][nf] = __builtin_amdgcn_mfma_f32_16x16x32_bf16(bv[nf], pa, o[rb][nf], 0, 0, 0);
        }
        __builtin_amdgcn_s_setprio(0);
    }

    // epilogue: lane q = q0 + w*32 + rb*16 + lr; d = 16nf + 4g + j (contiguous)
#pragma unroll
    for (int rb = 0; rb < 2; ++rb) {
        float lv = __shfl(o[rb][3][0], lr, 64);   // l from g=0 lane of this q
        int qr = q0 + w * 32 + rb * 16 + lr;
        if (qr < NTOK) {
            float inv = 1.f / lv;
            size_t rbse = ((size_t)b * NTOK + qr) * QKV_COLS;
#pragma unroll
            for (int nf = 0; nf < 3; ++nf) {
                ushort4 hi4, lo4;
#pragma unroll
                for (int j = 0; j < 4; ++j) {
                    float v = o[rb][nf][j] * inv;
                    ushort hv = f2b(v);
                    ((ushort*)&hi4)[j] = hv;
                    ((ushort*)&lo4)[j] = f2b(v - b2f(hv));
                }
                int c = h * HD + nf * 16 + 4 * g;
                *(ushort4*)&asplit[rbse + c] = hi4;
                *(ushort4*)&asplit[rbse + DIM + c] = lo4;
                *(ushort4*)&asplit[rbse + 2 * DIM + c] = hi4;
            }
        }
    }
}

// ---------------- launch ------------------------------------------------------
extern "C" void kernel_launch(void* const* d_in, const int* in_sizes, int n_in,
                              void* d_out, int out_size, void* d_ws, size_t ws_size,
                              hipStream_t stream) {
    const float* x   = (const float*)d_in[0];
    const int*   pos = (const int*)d_in[1];
    const float* Wq  = (const float*)d_in[2];
    const float* Wp  = (const float*)d_in[3];
    const float* bp  = (const float*)d_in[4];
    float* out = (float*)d_out;

    ushort* ws     = (ushort*)d_ws;
    ushort* x_bf   = ws;                                    // 6272*768 (later reused as vt)
    ushort* WqT    = x_bf + (size_t)ROWS * DIM;             // 2304*768
    ushort* WpT3   = WqT + (size_t)QKV_COLS * DIM;          // 768*2304
    ushort* qkv_bf = WpT3 + (size_t)DIM * QKV_COLS;         // 6272*2304
    ushort* asplit = qkv_bf + (size_t)ROWS * QKV_COLS;      // 6272*2304
    ushort* vt     = x_bf;   // alias: x_bf dead after gemm1; 4*768*1568 == 6272*768

    cast_f32_bf16<<<(ROWS * DIM / 4 + 255) / 256, 256, 0, stream>>>(x, x_bf, ROWS * DIM / 4);
    transpose_cast<<<dim3(QKV_COLS / 32, DIM / 32), dim3(32, 8), 0, stream>>>(Wq, WqT, DIM, QKV_COLS);
    split_transpose_wp<<<dim3(DIM / 32, DIM / 32), dim3(32, 8), 0, stream>>>(Wp, WpT3);

    // qkv = x @ W_qkv  (bf16 out)
    gemm_bf16<<<dim3(QKV_COLS / GBN, ROWS / GBM), 256, 0, stream>>>(
        x_bf, WqT, nullptr, qkv_bf, nullptr, ROWS, QKV_COLS, DIM);

    // vt[b][c][n] = V^T (overwrites x_bf, which is dead now)
    transpose_v<<<dim3(DIM / 32, NTOK / 32, BATCH), dim3(32, 8), 0, stream>>>(qkv_bf, vt);

    rope_bf16<<<(BATCH * NTOK * NHEADS * 3 + 255) / 256, 256, 0, stream>>>(qkv_bf, pos);

    attn_mfma<<<dim3(BATCH * NHEADS, (NTOK + QBLK - 1) / QBLK), 256, 0, stream>>>(qkv_bf, vt, asplit);

    // out = asplit @ WpT3^T + b  (split-bf16, K=2304, f32 out)
    gemm_bf16<<<dim3(DIM / GBN, ROWS / GBM), 256, 0, stream>>>(
        asplit, WpT3, out, nullptr, bp, ROWS, DIM, QKV_COLS);
}

// Round 12
// 179.417 us; speedup vs baseline: 1.2132x; 1.1196x over previous
//
#include <hip/hip_runtime.h>
#include <hip/hip_bf16.h>
#include <math.h>

#define DIM 768
#define NHEADS 16
#define HD 48
#define NTOK 1568
#define BATCH 4
#define ROWS (BATCH * NTOK)     // 6272
#define QKV_COLS (3 * DIM)      // 2304

typedef __attribute__((ext_vector_type(8))) short bf16x8;
typedef __attribute__((ext_vector_type(4))) float f32x4;

__device__ inline float b2f(ushort u) {
    union { float f; unsigned u; } v; v.u = ((unsigned)u) << 16; return v.f;
}
__device__ inline ushort f2b(float f) {
    union { float f; unsigned u; } v; v.f = f;
    unsigned r = v.u + 0x7fff + ((v.u >> 16) & 1);   // round-to-nearest-even
    return (ushort)(r >> 16);
}

// async global->LDS, 16B per lane; lds dest is wave-uniform base (+lane*16 by HW)
__device__ inline void gl16(const void* g, void* l) {
    __builtin_amdgcn_global_load_lds(
        (const __attribute__((address_space(1))) unsigned int*)g,
        (__attribute__((address_space(3))) unsigned int*)l, 16, 0, 0);
}

// ---------------- cast fp32 -> bf16 (vectorized) -----------------------------
__global__ void cast_f32_bf16(const float* __restrict__ in, ushort* __restrict__ out, int n4) {
    int i = blockIdx.x * blockDim.x + threadIdx.x;
    if (i >= n4) return;
    float4 v = ((const float4*)in)[i];
    ushort4 o;
    o.x = f2b(v.x); o.y = f2b(v.y); o.z = f2b(v.z); o.w = f2b(v.w);
    ((ushort4*)out)[i] = o;
}

// ---------------- transpose-cast: in[R][C] f32 -> out[C][R] bf16 -------------
__global__ void transpose_cast(const float* __restrict__ in, ushort* __restrict__ out,
                               int R, int C) {
    __shared__ ushort tile[32][33];
    int tx = threadIdx.x, ty = threadIdx.y;
    int c0 = blockIdx.x * 32, r0 = blockIdx.y * 32;
#pragma unroll
    for (int k = 0; k < 4; ++k)
        tile[ty + 8 * k][tx] = f2b(in[(size_t)(r0 + ty + 8 * k) * C + c0 + tx]);
    __syncthreads();
#pragma unroll
    for (int k = 0; k < 4; ++k)
        out[(size_t)(c0 + ty + 8 * k) * R + r0 + tx] = tile[tx][ty + 8 * k];
}

// ------- split-transpose W_proj [768][768] f32 -> out[768][2304] = [wh|wh|wl]
__global__ void split_transpose_wp(const float* __restrict__ in, ushort* __restrict__ out) {
    __shared__ float tile[32][33];
    int tx = threadIdx.x, ty = threadIdx.y;
    int c0 = blockIdx.x * 32, r0 = blockIdx.y * 32;   // r = k, c = n
#pragma unroll
    for (int k = 0; k < 4; ++k)
        tile[ty + 8 * k][tx] = in[(size_t)(r0 + ty + 8 * k) * DIM + c0 + tx];
    __syncthreads();
#pragma unroll
    for (int k = 0; k < 4; ++k) {
        float w = tile[tx][ty + 8 * k];
        ushort hi = f2b(w);
        ushort lo = f2b(w - b2f(hi));
        size_t base = (size_t)(c0 + ty + 8 * k) * QKV_COLS + r0 + tx;
        out[base] = hi; out[base + DIM] = hi; out[base + 2 * DIM] = lo;
    }
}

// ------- transpose V slice of qkv: vt[b][c][n] = qkv[b][n][1536+c], c in [0,768)
__global__ void transpose_v(const ushort* __restrict__ qkv, ushort* __restrict__ vt) {
    __shared__ ushort tile[32][33];
    int tx = threadIdx.x, ty = threadIdx.y;   // 32x8
    int c0 = blockIdx.x * 32, n0 = blockIdx.y * 32, b = blockIdx.z;
    const ushort* src = qkv + (size_t)b * NTOK * QKV_COLS + 2 * DIM;
#pragma unroll
    for (int k = 0; k < 4; ++k)
        tile[ty + 8 * k][tx] = src[(size_t)(n0 + ty + 8 * k) * QKV_COLS + c0 + tx];
    __syncthreads();
    ushort* dst = vt + (size_t)b * DIM * NTOK;
#pragma unroll
    for (int k = 0; k < 4; ++k)
        dst[(size_t)(c0 + ty + 8 * k) * NTOK + n0 + tx] = tile[tx][ty + 8 * k];
}

// ---------------- bf16 MFMA GEMM: C[M][N] = A[M][K] * Bt[N][K]^T -------------
// Templated on BM (BN=128, BK=64). Double-buffered gload_lds staging, depth-1
// issue-early pipeline, ONE barrier per K-iter:
//   iter t: vmcnt(0) [stage-t landed] -> barrier [tile ready; compute(t-1)
//   done by all waves -> buf t+1 reusable] -> issue STAGE(t+1) -> compute(t).
#define GBK 64

template <int BM>
__global__ __launch_bounds__(256) void gemm_bf16(
    const ushort* __restrict__ A, const ushort* __restrict__ Bt,
    float* __restrict__ Cf, ushort* __restrict__ Cb,
    const float* __restrict__ bias, int M, int N, int K) {
    constexpr int MI = BM / 32;           // A m-frags per wave; A chunks/thread
    __shared__ ushort sA[2][BM * 64];
    __shared__ ushort sB[2][128 * 64];
    const int tid = threadIdx.x;
    const int wid = tid >> 6, lane = tid & 63;
    const int wm = wid >> 1, wn = wid & 1;          // 2x2 wave grid
    const int m0 = blockIdx.y * BM, n0 = blockIdx.x * 128;
    const int lr = lane & 15, g = lane >> 4;

    auto STAGE = [&](int buf, int k0) {
#pragma unroll
        for (int i = 0; i < MI; ++i) {      // A: BM*8 chunks
            int c = tid + 256 * i;
            int row = c >> 3;
            int ch = (c & 7) ^ (row & 7);   // source pre-swizzle
            gl16(&A[(size_t)(m0 + row) * K + k0 + ch * 8], &sA[buf][(c & ~63) * 8]);
        }
#pragma unroll
        for (int i = 0; i < 4; ++i) {       // B: 1024 chunks
            int c = tid + 256 * i;
            int row = c >> 3;
            int ch = (c & 7) ^ (row & 7);
            gl16(&Bt[(size_t)(n0 + row) * K + k0 + ch * 8], &sB[buf][(c & ~63) * 8]);
        }
    };

    f32x4 acc[MI][4] = {};
    const int NK = K / GBK;
    STAGE(0, 0);
    for (int t = 0; t < NK; ++t) {
        const int cur = t & 1;
        asm volatile("s_waitcnt vmcnt(0)" ::: "memory");
        __builtin_amdgcn_s_barrier();
        if (t + 1 < NK) STAGE(cur ^ 1, (t + 1) * GBK);
#pragma unroll
        for (int k2 = 0; k2 < GBK; k2 += 32) {
            bf16x8 af[MI], bg[4];
#pragma unroll
            for (int f = 0; f < MI; ++f) {
                int ra = wm * (BM / 2) + f * 16 + lr;
                int ba = (ra * 128 + k2 * 2 + g * 16) ^ ((ra & 7) << 4);
                af[f] = *(const bf16x8*)((const char*)sA[cur] + ba);
            }
#pragma unroll
            for (int f = 0; f < 4; ++f) {
                int rb = wn * 64 + f * 16 + lr;
                int bb = (rb * 128 + k2 * 2 + g * 16) ^ ((rb & 7) << 4);
                bg[f] = *(const bf16x8*)((const char*)sB[cur] + bb);
            }
#pragma unroll
            for (int mi = 0; mi < MI; ++mi)
#pragma unroll
                for (int ni = 0; ni < 4; ++ni)
                    acc[mi][ni] = __builtin_amdgcn_mfma_f32_16x16x32_bf16(
                        af[mi], bg[ni], acc[mi][ni], 0, 0, 0);
        }
    }
    const int cr = g * 4;
#pragma unroll
    for (int mi = 0; mi < MI; ++mi)
#pragma unroll
        for (int ni = 0; ni < 4; ++ni) {
            int col = n0 + wn * 64 + ni * 16 + lr;
#pragma unroll
            for (int j = 0; j < 4; ++j) {
                int row = m0 + wm * (BM / 2) + mi * 16 + cr + j;
                float v = acc[mi][ni][j];
                if (Cf) {
                    if (bias) v += bias[col];
                    Cf[(size_t)row * N + col] = v;
                } else {
                    Cb[(size_t)row * N + col] = f2b(v);
                }
            }
        }
}

// ---------------- RoPE 3D, vectorized: thread = (b,n,h,axis), 8 pairs --------
__global__ void rope_bf16(ushort* __restrict__ qkv, const int* __restrict__ pos) {
    int idx = blockIdx.x * blockDim.x + threadIdx.x;
    const int total = BATCH * NTOK * NHEADS * 3;   // 301056
    if (idx >= total) return;
    int axis = idx % 3; int t = idx / 3;
    int h = t & 15; t >>= 4;
    int n = t % NTOK; int b = t / NTOK;

    float p = (float)pos[n * 3 + axis];
    size_t base = ((size_t)b * NTOK + n) * QKV_COLS + h * HD + axis * 16;

    bf16x8 qlo = *(bf16x8*)&qkv[base],       qhi = *(bf16x8*)&qkv[base + 8];
    bf16x8 klo = *(bf16x8*)&qkv[base + DIM], khi = *(bf16x8*)&qkv[base + DIM + 8];

    const float RINV = 0.31622776601683794f;   // 10000^(-1/8)
    float fj = 1.0f;
#pragma unroll
    for (int j = 0; j < 8; ++j) {
        float s, c; __sincosf(p * fj, &s, &c); fj *= RINV;
        float q1 = b2f((ushort)qlo[j]), q2 = b2f((ushort)qhi[j]);
        qlo[j] = (short)f2b(q1 * c - q2 * s);
        qhi[j] = (short)f2b(q2 * c + q1 * s);
        float k1 = b2f((ushort)klo[j]), k2 = b2f((ushort)khi[j]);
        klo[j] = (short)f2b(k1 * c - k2 * s);
        khi[j] = (short)f2b(k2 * c + k1 * s);
    }
    *(bf16x8*)&qkv[base] = qlo;       *(bf16x8*)&qkv[base + 8] = qhi;
    *(bf16x8*)&qkv[base + DIM] = klo; *(bf16x8*)&qkv[base + DIM + 8] = khi;
}

// ---------------- MFMA flash attention ---------------------------------------
// Grid: (64 bh, 13 q-tiles), bh%8 = XCD. QBLK=128 (wave owns 32 q-rows).
// TRIPLE-buffered K/V via global_load_lds, depth-2 pipeline, ONE barrier/tile.
// Fixed-offset exp2 softmax; -32 in MFMA C-init; l via ones-row (V^T row 48).
#define QBLK 128
#define KVB 32
#define NT (NTOK / KVB)   // 49
#define PP 40             // sP pitch

__global__ __launch_bounds__(256) void attn_mfma(const ushort* __restrict__ qkv,
                                                 const ushort* __restrict__ vt,
                                                 ushort* __restrict__ asplit) {
    __shared__ ushort sK3[3][KVB * 64];   // [32][64] linear, 12 KB
    __shared__ ushort sV3[3][64 * 32];    // rows 0..47 V^T, 48 = ones; 12 KB
    __shared__ ushort sP[4][32 * PP];     // 10 KB
    const int tid = threadIdx.x, w = tid >> 6, lane = tid & 63;
    const int b = blockIdx.x >> 4, h = blockIdx.x & 15;
    const int q0 = blockIdx.y * QBLK;
    const size_t bbase = (size_t)b * NTOK * QKV_COLS;
    const size_t vbase = ((size_t)b * DIM + h * HD) * NTOK;
    const int lr = lane & 15, g = lane >> 4, lk = g << 3;
    const float qs = 0.14433756729740643f * 1.4426950408889634f;  // 1/sqrt(48)*log2e
    const float M2 = 32.0f;   // fixed exp2-domain offset (folded into C-init)

    // ones-row for l-accumulation (row 48 of all 3 V buffers)
    if (tid < 32) {
        sV3[0][48 * 32 + tid] = 0x3F80;
        sV3[1][48 * 32 + tid] = 0x3F80;
        sV3[2][48 * 32 + tid] = 0x3F80;
    }
    asm volatile("s_waitcnt lgkmcnt(0)" ::: "memory");

    // Q direct to registers, scaled by qs; cols >= 48 zero (nulls K garbage)
    bf16x8 aq[2][2];
#pragma unroll
    for (int rb = 0; rb < 2; ++rb) {
        int qr = q0 + w * 32 + rb * 16 + lr;
        if (qr >= NTOK) qr = NTOK - 1;
        const ushort* qp = &qkv[bbase + (size_t)qr * QKV_COLS + h * HD];
        bf16x8 r0 = *(const bf16x8*)&qp[lk];
        bf16x8 r1 = {};
        if (g < 2) r1 = *(const bf16x8*)&qp[32 + lk];
#pragma unroll
        for (int e = 0; e < 8; ++e) {
            r0[e] = (short)f2b(b2f((ushort)r0[e]) * qs);
            r1[e] = (short)f2b(b2f((ushort)r1[e]) * qs);
        }
        aq[rb][0] = r0; aq[rb][1] = r1;
    }

    // stage K (256 chunks) + V (192 chunks) for tile kv0 into buffer buf
    auto STAGE = [&](int buf, int kv0) {
        {   // K: chunk c = tid; row = c>>3; source chunk swizzled
            int c = tid, row = c >> 3;
            int ch = (c & 7) ^ (row & 7);
            gl16(&qkv[bbase + (size_t)(kv0 + row) * QKV_COLS + DIM + h * HD + ch * 8],
                 &sK3[buf][(c & ~63) * 8]);
        }
        if (lane < 48) {   // V: wave w stages chunks w*48..w*48+47 (rows 0..47)
            int c = w * 48 + lane, d = c >> 2;
            int cc = (c & 3) ^ ((d >> 1) & 3);
            gl16(&vt[vbase + (size_t)d * NTOK + kv0 + cc * 8],
                 &sV3[buf][w * 384]);
        }
    };

    f32x4 o[2][4] = {};   // per rb: d 0..47 in [0..2]; [3][0] (g=0) = l

    STAGE(0, 0);
    STAGE(1, KVB);
    for (int t = 0; t < NT; ++t) {
        const int cur = t % 3;
        if (t + 1 < NT) asm volatile("s_waitcnt vmcnt(2)" ::: "memory");
        else            asm volatile("s_waitcnt vmcnt(0)" ::: "memory");
        __builtin_amdgcn_s_barrier();
        if (t + 2 < NT) STAGE((t + 2) % 3, (t + 2) * KVB);

        // S^T = K Q^T - 32: lane: q = rb*16+lr, keys = f*16 + 4g + j
        bf16x8 bk[2][2];
#pragma unroll
        for (int f = 0; f < 2; ++f)
#pragma unroll
            for (int ks = 0; ks < 2; ++ks) {
                int row = f * 16 + lr;
                int byt = (row * 128 + ks * 64 + g * 16) ^ ((lr & 7) << 4);
                bk[f][ks] = *(const bf16x8*)((const char*)sK3[cur] + byt);
            }
        f32x4 sacc[2][2] = {{{-M2, -M2, -M2, -M2}, {-M2, -M2, -M2, -M2}},
                            {{-M2, -M2, -M2, -M2}, {-M2, -M2, -M2, -M2}}};
        __builtin_amdgcn_s_setprio(1);
#pragma unroll
        for (int rb = 0; rb < 2; ++rb)
#pragma unroll
            for (int f = 0; f < 2; ++f) {
                sacc[rb][f] = __builtin_amdgcn_mfma_f32_16x16x32_bf16(bk[f][0], aq[rb][0], sacc[rb][f], 0, 0, 0);
                sacc[rb][f] = __builtin_amdgcn_mfma_f32_16x16x32_bf16(bk[f][1], aq[rb][1], sacc[rb][f], 0, 0, 0);
            }
        __builtin_amdgcn_s_setprio(0);

        // p = 2^(s2-32); pack adjacent-key pairs -> b64 stores to sP[q][key]
#pragma unroll
        for (int rb = 0; rb < 2; ++rb)
#pragma unroll
            for (int f = 0; f < 2; ++f) {
                float p[4];
#pragma unroll
                for (int j = 0; j < 4; ++j) {
                    float pv;
                    asm("v_exp_f32 %0, %1" : "=v"(pv) : "v"(sacc[rb][f][j]));
                    p[j] = pv;
                }
                uint u0, u1;
                asm("v_cvt_pk_bf16_f32 %0, %1, %2" : "=v"(u0) : "v"(p[0]), "v"(p[1]));
                asm("v_cvt_pk_bf16_f32 %0, %1, %2" : "=v"(u1) : "v"(p[2]), "v"(p[3]));
                uint2 uu; uu.x = u0; uu.y = u1;
                *(uint2*)&sP[w][(rb * 16 + lr) * PP + f * 16 + 4 * g] = uu;
            }

        // PV (swapped): o^T = mfma(V^T, P): lane: q = lr, d = 16nf + 4g + j
        // nf=3 row 48 = ones -> accumulates l into o[rb][3] (g=0,j=0)
        bf16x8 bv[4];
#pragma unroll
        for (int nf = 0; nf < 4; ++nf) {
            int row = nf * 16 + lr;
            int byt = (row * 64 + g * 16) ^ (((lr >> 1) & 3) << 4);
            bv[nf] = *(const bf16x8*)((const char*)sV3[cur] + byt);
        }
        __builtin_amdgcn_s_setprio(1);
#pragma unroll
        for (int rb = 0; rb < 2; ++rb) {
            bf16x8 pa = *(const bf16x8*)&sP[w][(rb * 16 + lr) * PP + lk];
#pragma unroll
            for (int nf = 0; nf < 4; ++nf)
                o[rb][nf] = __builtin_amdgcn_mfma_f32_16x16x32_bf16(bv[nf], pa, o[rb][nf], 0, 0, 0);
        }
        __builtin_amdgcn_s_setprio(0);
    }

    // epilogue: lane q = q0 + w*32 + rb*16 + lr; d = 16nf + 4g + j (contiguous)
#pragma unroll
    for (int rb = 0; rb < 2; ++rb) {
        float lv = __shfl(o[rb][3][0], lr, 64);   // l from g=0 lane of this q
        int qr = q0 + w * 32 + rb * 16 + lr;
        if (qr < NTOK) {
            float inv = 1.f / lv;
            size_t rbse = ((size_t)b * NTOK + qr) * QKV_COLS;
#pragma unroll
            for (int nf = 0; nf < 3; ++nf) {
                ushort4 hi4, lo4;
#pragma unroll
                for (int j = 0; j < 4; ++j) {
                    float v = o[rb][nf][j] * inv;
                    ushort hv = f2b(v);
                    ((ushort*)&hi4)[j] = hv;
                    ((ushort*)&lo4)[j] = f2b(v - b2f(hv));
                }
                int c = h * HD + nf * 16 + 4 * g;
                *(ushort4*)&asplit[rbse + c] = hi4;
                *(ushort4*)&asplit[rbse + DIM + c] = lo4;
                *(ushort4*)&asplit[rbse + 2 * DIM + c] = hi4;
            }
        }
    }
}

// ---------------- launch ------------------------------------------------------
extern "C" void kernel_launch(void* const* d_in, const int* in_sizes, int n_in,
                              void* d_out, int out_size, void* d_ws, size_t ws_size,
                              hipStream_t stream) {
    const float* x   = (const float*)d_in[0];
    const int*   pos = (const int*)d_in[1];
    const float* Wq  = (const float*)d_in[2];
    const float* Wp  = (const float*)d_in[3];
    const float* bp  = (const float*)d_in[4];
    float* out = (float*)d_out;

    ushort* ws     = (ushort*)d_ws;
    ushort* x_bf   = ws;                                    // 6272*768 (later reused as vt)
    ushort* WqT    = x_bf + (size_t)ROWS * DIM;             // 2304*768
    ushort* WpT3   = WqT + (size_t)QKV_COLS * DIM;          // 768*2304
    ushort* qkv_bf = WpT3 + (size_t)DIM * QKV_COLS;         // 6272*2304
    ushort* asplit = qkv_bf + (size_t)ROWS * QKV_COLS;      // 6272*2304
    ushort* vt     = x_bf;   // alias: x_bf dead after gemm1; 4*768*1568 == 6272*768

    cast_f32_bf16<<<(ROWS * DIM / 4 + 255) / 256, 256, 0, stream>>>(x, x_bf, ROWS * DIM / 4);
    transpose_cast<<<dim3(QKV_COLS / 32, DIM / 32), dim3(32, 8), 0, stream>>>(Wq, WqT, DIM, QKV_COLS);
    split_transpose_wp<<<dim3(DIM / 32, DIM / 32), dim3(32, 8), 0, stream>>>(Wp, WpT3);

    // qkv = x @ W_qkv  (bf16 out)
    gemm_bf16<128><<<dim3(QKV_COLS / 128, ROWS / 128), 256, 0, stream>>>(
        x_bf, WqT, nullptr, qkv_bf, nullptr, ROWS, QKV_COLS, DIM);

    // vt[b][c][n] = V^T (overwrites x_bf, which is dead now)
    transpose_v<<<dim3(DIM / 32, NTOK / 32, BATCH), dim3(32, 8), 0, stream>>>(qkv_bf, vt);

    rope_bf16<<<(BATCH * NTOK * NHEADS * 3 + 255) / 256, 256, 0, stream>>>(qkv_bf, pos);

    attn_mfma<<<dim3(BATCH * NHEADS, (NTOK + QBLK - 1) / QBLK), 256, 0, stream>>>(qkv_bf, vt, asplit);

    // out = asplit @ WpT3^T + b  (split-bf16, K=2304, f32 out; BM=64 -> 588 blocks)
    gemm_bf16<64><<<dim3(DIM / 128, ROWS / 64), 256, 0, stream>>>(
        asplit, WpT3, out, nullptr, bp, ROWS, DIM, QKV_COLS);
}

// Round 14
// 152.684 us; speedup vs baseline: 1.4256x; 1.1751x over previous
//
#include <hip/hip_runtime.h>
#include <hip/hip_bf16.h>
#include <math.h>

#define DIM 768
#define NHEADS 16
#define HD 48
#define NTOK 1568
#define BATCH 4
#define ROWS (BATCH * NTOK)     // 6272
#define QKV_COLS (3 * DIM)      // 2304

typedef __attribute__((ext_vector_type(8))) _Float16 f16x8;
typedef __attribute__((ext_vector_type(2))) __fp16 fp16v2;
typedef __attribute__((ext_vector_type(4))) float f32x4;

__device__ inline ushort f2h(float f) {
    union { _Float16 h; ushort u; } v; v.h = (_Float16)f; return v.u;
}
__device__ inline float h2f(ushort u) {
    union { _Float16 h; ushort u; } v; v.u = u; return (float)v.h;
}

// async global->LDS, 16B per lane; lds dest is wave-uniform base (+lane*16 by HW)
__device__ inline void gl16(const void* g, void* l) {
    __builtin_amdgcn_global_load_lds(
        (const __attribute__((address_space(1))) unsigned int*)g,
        (__attribute__((address_space(3))) unsigned int*)l, 16, 0, 0);
}

// ---------------- cast fp32 -> fp16 (vectorized) -----------------------------
__global__ void cast_f32_f16(const float* __restrict__ in, ushort* __restrict__ out, int n4) {
    int i = blockIdx.x * blockDim.x + threadIdx.x;
    if (i >= n4) return;
    float4 v = ((const float4*)in)[i];
    ushort4 o;
    o.x = f2h(v.x); o.y = f2h(v.y); o.z = f2h(v.z); o.w = f2h(v.w);
    ((ushort4*)out)[i] = o;
}

// ---------------- transpose-cast: in[R][C] f32 -> out[C][R] fp16 -------------
__global__ void transpose_cast(const float* __restrict__ in, ushort* __restrict__ out,
                               int R, int C) {
    __shared__ ushort tile[32][33];
    int tx = threadIdx.x, ty = threadIdx.y;
    int c0 = blockIdx.x * 32, r0 = blockIdx.y * 32;
#pragma unroll
    for (int k = 0; k < 4; ++k)
        tile[ty + 8 * k][tx] = f2h(in[(size_t)(r0 + ty + 8 * k) * C + c0 + tx]);
    __syncthreads();
#pragma unroll
    for (int k = 0; k < 4; ++k)
        out[(size_t)(c0 + ty + 8 * k) * R + r0 + tx] = tile[tx][ty + 8 * k];
}

// ------- transpose V slice of qkv: vt[b][c][n] = qkv[b][n][1536+c], c in [0,768)
__global__ void transpose_v(const ushort* __restrict__ qkv, ushort* __restrict__ vt) {
    __shared__ ushort tile[32][33];
    int tx = threadIdx.x, ty = threadIdx.y;   // 32x8
    int c0 = blockIdx.x * 32, n0 = blockIdx.y * 32, b = blockIdx.z;
    const ushort* src = qkv + (size_t)b * NTOK * QKV_COLS + 2 * DIM;
#pragma unroll
    for (int k = 0; k < 4; ++k)
        tile[ty + 8 * k][tx] = src[(size_t)(n0 + ty + 8 * k) * QKV_COLS + c0 + tx];
    __syncthreads();
    ushort* dst = vt + (size_t)b * DIM * NTOK;
#pragma unroll
    for (int k = 0; k < 4; ++k)
        dst[(size_t)(c0 + ty + 8 * k) * NTOK + n0 + tx] = tile[tx][ty + 8 * k];
}

// ---------------- fp16 MFMA GEMM: C[M][N] = A[M][K] * Bt[N][K]^T -------------
// Templated on BM (BN=128, BK=64). Double-buffered gload_lds staging, depth-1
// issue-early pipeline, ONE barrier per K-iter.
#define GBK 64

template <int BM>
__global__ __launch_bounds__(256) void gemm_f16(
    const ushort* __restrict__ A, const ushort* __restrict__ Bt,
    float* __restrict__ Cf, ushort* __restrict__ Cb,
    const float* __restrict__ bias, int M, int N, int K) {
    constexpr int MI = BM / 32;           // A m-frags per wave; A chunks/thread
    __shared__ ushort sA[2][BM * 64];
    __shared__ ushort sB[2][128 * 64];
    const int tid = threadIdx.x;
    const int wid = tid >> 6, lane = tid & 63;
    const int wm = wid >> 1, wn = wid & 1;          // 2x2 wave grid
    const int m0 = blockIdx.y * BM, n0 = blockIdx.x * 128;
    const int lr = lane & 15, g = lane >> 4;

    auto STAGE = [&](int buf, int k0) {
#pragma unroll
        for (int i = 0; i < MI; ++i) {      // A: BM*8 chunks
            int c = tid + 256 * i;
            int row = c >> 3;
            int ch = (c & 7) ^ (row & 7);   // source pre-swizzle
            gl16(&A[(size_t)(m0 + row) * K + k0 + ch * 8], &sA[buf][(c & ~63) * 8]);
        }
#pragma unroll
        for (int i = 0; i < 4; ++i) {       // B: 1024 chunks
            int c = tid + 256 * i;
            int row = c >> 3;
            int ch = (c & 7) ^ (row & 7);
            gl16(&Bt[(size_t)(n0 + row) * K + k0 + ch * 8], &sB[buf][(c & ~63) * 8]);
        }
    };

    f32x4 acc[MI][4] = {};
    const int NK = K / GBK;
    STAGE(0, 0);
    for (int t = 0; t < NK; ++t) {
        const int cur = t & 1;
        asm volatile("s_waitcnt vmcnt(0)" ::: "memory");
        __builtin_amdgcn_s_barrier();
        if (t + 1 < NK) STAGE(cur ^ 1, (t + 1) * GBK);
#pragma unroll
        for (int k2 = 0; k2 < GBK; k2 += 32) {
            f16x8 af[MI], bg[4];
#pragma unroll
            for (int f = 0; f < MI; ++f) {
                int ra = wm * (BM / 2) + f * 16 + lr;
                int ba = (ra * 128 + k2 * 2 + g * 16) ^ ((ra & 7) << 4);
                af[f] = *(const f16x8*)((const char*)sA[cur] + ba);
            }
#pragma unroll
            for (int f = 0; f < 4; ++f) {
                int rb = wn * 64 + f * 16 + lr;
                int bb = (rb * 128 + k2 * 2 + g * 16) ^ ((rb & 7) << 4);
                bg[f] = *(const f16x8*)((const char*)sB[cur] + bb);
            }
#pragma unroll
            for (int mi = 0; mi < MI; ++mi)
#pragma unroll
                for (int ni = 0; ni < 4; ++ni)
                    acc[mi][ni] = __builtin_amdgcn_mfma_f32_16x16x32_f16(
                        af[mi], bg[ni], acc[mi][ni], 0, 0, 0);
        }
    }
    const int cr = g * 4;
#pragma unroll
    for (int mi = 0; mi < MI; ++mi)
#pragma unroll
        for (int ni = 0; ni < 4; ++ni) {
            int col = n0 + wn * 64 + ni * 16 + lr;
#pragma unroll
            for (int j = 0; j < 4; ++j) {
                int row = m0 + wm * (BM / 2) + mi * 16 + cr + j;
                float v = acc[mi][ni][j];
                if (Cf) {
                    if (bias) v += bias[col];
                    Cf[(size_t)row * N + col] = v;
                } else {
                    Cb[(size_t)row * N + col] = f2h(v);
                }
            }
        }
}

// ---------------- RoPE 3D, vectorized: thread = (b,n,h,axis), 8 pairs --------
__global__ void rope_f16(ushort* __restrict__ qkv, const int* __restrict__ pos) {
    int idx = blockIdx.x * blockDim.x + threadIdx.x;
    const int total = BATCH * NTOK * NHEADS * 3;   // 301056
    if (idx >= total) return;
    int axis = idx % 3; int t = idx / 3;
    int h = t & 15; t >>= 4;
    int n = t % NTOK; int b = t / NTOK;

    float p = (float)pos[n * 3 + axis];
    size_t base = ((size_t)b * NTOK + n) * QKV_COLS + h * HD + axis * 16;

    ushort lo[8], hi[8], klo[8], khi[8];
    *(ushort4*)&lo[0] = *(ushort4*)&qkv[base];
    *(ushort4*)&lo[4] = *(ushort4*)&qkv[base + 4];
    *(ushort4*)&hi[0] = *(ushort4*)&qkv[base + 8];
    *(ushort4*)&hi[4] = *(ushort4*)&qkv[base + 12];
    *(ushort4*)&klo[0] = *(ushort4*)&qkv[base + DIM];
    *(ushort4*)&klo[4] = *(ushort4*)&qkv[base + DIM + 4];
    *(ushort4*)&khi[0] = *(ushort4*)&qkv[base + DIM + 8];
    *(ushort4*)&khi[4] = *(ushort4*)&qkv[base + DIM + 12];

    const float RINV = 0.31622776601683794f;   // 10000^(-1/8)
    float fj = 1.0f;
#pragma unroll
    for (int j = 0; j < 8; ++j) {
        float s, c; __sincosf(p * fj, &s, &c); fj *= RINV;
        float q1 = h2f(lo[j]), q2 = h2f(hi[j]);
        lo[j] = f2h(q1 * c - q2 * s);
        hi[j] = f2h(q2 * c + q1 * s);
        float k1 = h2f(klo[j]), k2 = h2f(khi[j]);
        klo[j] = f2h(k1 * c - k2 * s);
        khi[j] = f2h(k2 * c + k1 * s);
    }
    *(ushort4*)&qkv[base] = *(ushort4*)&lo[0];
    *(ushort4*)&qkv[base + 4] = *(ushort4*)&lo[4];
    *(ushort4*)&qkv[base + 8] = *(ushort4*)&hi[0];
    *(ushort4*)&qkv[base + 12] = *(ushort4*)&hi[4];
    *(ushort4*)&qkv[base + DIM] = *(ushort4*)&klo[0];
    *(ushort4*)&qkv[base + DIM + 4] = *(ushort4*)&klo[4];
    *(ushort4*)&qkv[base + DIM + 8] = *(ushort4*)&khi[0];
    *(ushort4*)&qkv[base + DIM + 12] = *(ushort4*)&khi[4];
}

// ---------------- MFMA flash attention (fp16) --------------------------------
// Grid: (64 bh, 13 q-tiles), bh%8 = XCD. QBLK=128 (wave owns 32 q-rows).
// TRIPLE-buffered K/V via global_load_lds, depth-2 pipeline, ONE barrier/tile.
// Fixed-offset exp2 softmax (M2=14: dominant P in fp16-normal range; P<2^-24
// carries relative weight <2^-12 of row max -> flush-to-zero harmless);
// -M2 in MFMA C-init; l via ones-row (V^T row 48 = 1.0h).
#define QBLK 128
#define KVB 32
#define NT (NTOK / KVB)   // 49
#define PP 40             // sP pitch

__global__ __launch_bounds__(256) void attn_mfma(const ushort* __restrict__ qkv,
                                                 const ushort* __restrict__ vt,
                                                 ushort* __restrict__ aout) {
    __shared__ ushort sK3[3][KVB * 64];   // [32][64] linear, 12 KB
    __shared__ ushort sV3[3][64 * 32];    // rows 0..47 V^T, 48 = ones; 12 KB
    __shared__ ushort sP[4][32 * PP];     // 10 KB
    const int tid = threadIdx.x, w = tid >> 6, lane = tid & 63;
    const int b = blockIdx.x >> 4, h = blockIdx.x & 15;
    const int q0 = blockIdx.y * QBLK;
    const size_t bbase = (size_t)b * NTOK * QKV_COLS;
    const size_t vbase = ((size_t)b * DIM + h * HD) * NTOK;
    const int lr = lane & 15, g = lane >> 4, lk = g << 3;
    const float qs = 0.14433756729740643f * 1.4426950408889634f;  // 1/sqrt(48)*log2e
    const float M2 = 14.0f;   // fixed exp2-domain offset (folded into C-init)

    // ones-row for l-accumulation (row 48 of all 3 V buffers)
    if (tid < 32) {
        sV3[0][48 * 32 + tid] = 0x3C00;   // 1.0 fp16
        sV3[1][48 * 32 + tid] = 0x3C00;
        sV3[2][48 * 32 + tid] = 0x3C00;
    }
    asm volatile("s_waitcnt lgkmcnt(0)" ::: "memory");

    // Q direct to registers, scaled by qs; cols >= 48 zero (nulls K garbage)
    f16x8 aq[2][2];
#pragma unroll
    for (int rb = 0; rb < 2; ++rb) {
        int qr = q0 + w * 32 + rb * 16 + lr;
        if (qr >= NTOK) qr = NTOK - 1;
        const ushort* qp = &qkv[bbase + (size_t)qr * QKV_COLS + h * HD];
        ushort r0[8], r1[8];
        *(ushort4*)&r0[0] = *(const ushort4*)&qp[lk];
        *(ushort4*)&r0[4] = *(const ushort4*)&qp[lk + 4];
        if (g < 2) {
            *(ushort4*)&r1[0] = *(const ushort4*)&qp[32 + lk];
            *(ushort4*)&r1[4] = *(const ushort4*)&qp[32 + lk + 4];
        } else {
#pragma unroll
            for (int e = 0; e < 8; ++e) r1[e] = 0;
        }
        f16x8 a0, a1;
#pragma unroll
        for (int e = 0; e < 8; ++e) {
            a0[e] = (_Float16)(h2f(r0[e]) * qs);
            a1[e] = (_Float16)(h2f(r1[e]) * qs);
        }
        aq[rb][0] = a0; aq[rb][1] = a1;
    }

    // stage K (256 chunks) + V (192 chunks) for tile kv0 into buffer buf
    auto STAGE = [&](int buf, int kv0) {
        {   // K: chunk c = tid; row = c>>3; source chunk swizzled
            int c = tid, row = c >> 3;
            int ch = (c & 7) ^ (row & 7);
            gl16(&qkv[bbase + (size_t)(kv0 + row) * QKV_COLS + DIM + h * HD + ch * 8],
                 &sK3[buf][(c & ~63) * 8]);
        }
        if (lane < 48) {   // V: wave w stages chunks w*48..w*48+47 (rows 0..47)
            int c = w * 48 + lane, d = c >> 2;
            int cc = (c & 3) ^ ((d >> 1) & 3);
            gl16(&vt[vbase + (size_t)d * NTOK + kv0 + cc * 8],
                 &sV3[buf][w * 384]);
        }
    };

    f32x4 o[2][4] = {};   // per rb: d 0..47 in [0..2]; [3][0] (g=0) = l

    STAGE(0, 0);
    STAGE(1, KVB);
    for (int t = 0; t < NT; ++t) {
        const int cur = t % 3;
        if (t + 1 < NT) asm volatile("s_waitcnt vmcnt(2)" ::: "memory");
        else            asm volatile("s_waitcnt vmcnt(0)" ::: "memory");
        __builtin_amdgcn_s_barrier();
        if (t + 2 < NT) STAGE((t + 2) % 3, (t + 2) * KVB);

        // S^T = K Q^T - M2: lane: q = rb*16+lr, keys = f*16 + 4g + j
        f16x8 bk[2][2];
#pragma unroll
        for (int f = 0; f < 2; ++f)
#pragma unroll
            for (int ks = 0; ks < 2; ++ks) {
                int row = f * 16 + lr;
                int byt = (row * 128 + ks * 64 + g * 16) ^ ((lr & 7) << 4);
                bk[f][ks] = *(const f16x8*)((const char*)sK3[cur] + byt);
            }
        f32x4 sacc[2][2] = {{{-M2, -M2, -M2, -M2}, {-M2, -M2, -M2, -M2}},
                            {{-M2, -M2, -M2, -M2}, {-M2, -M2, -M2, -M2}}};
        __builtin_amdgcn_s_setprio(1);
#pragma unroll
        for (int rb = 0; rb < 2; ++rb)
#pragma unroll
            for (int f = 0; f < 2; ++f) {
                sacc[rb][f] = __builtin_amdgcn_mfma_f32_16x16x32_f16(bk[f][0], aq[rb][0], sacc[rb][f], 0, 0, 0);
                sacc[rb][f] = __builtin_amdgcn_mfma_f32_16x16x32_f16(bk[f][1], aq[rb][1], sacc[rb][f], 0, 0, 0);
            }
        __builtin_amdgcn_s_setprio(0);

        // p = 2^(s2-M2); pack adjacent-key pairs (cvt_pkrtz) -> b64 stores
#pragma unroll
        for (int rb = 0; rb < 2; ++rb)
#pragma unroll
            for (int f = 0; f < 2; ++f) {
                float p[4];
#pragma unroll
                for (int j = 0; j < 4; ++j) {
                    float pv;
                    asm("v_exp_f32 %0, %1" : "=v"(pv) : "v"(sacc[rb][f][j]));
                    p[j] = pv;
                }
                union { fp16v2 h; uint u; } c0, c1;
                c0.h = __builtin_amdgcn_cvt_pkrtz(p[0], p[1]);
                c1.h = __builtin_amdgcn_cvt_pkrtz(p[2], p[3]);
                uint2 uu; uu.x = c0.u; uu.y = c1.u;
                *(uint2*)&sP[w][(rb * 16 + lr) * PP + f * 16 + 4 * g] = uu;
            }

        // PV (swapped): o^T = mfma(V^T, P): lane: q = lr, d = 16nf + 4g + j
        // nf=3 row 48 = ones -> accumulates l into o[rb][3] (g=0,j=0)
        f16x8 bv[4];
#pragma unroll
        for (int nf = 0; nf < 4; ++nf) {
            int row = nf * 16 + lr;
            int byt = (row * 64 + g * 16) ^ (((lr >> 1) & 3) << 4);
            bv[nf] = *(const f16x8*)((const char*)sV3[cur] + byt);
        }
        __builtin_amdgcn_s_setprio(1);
#pragma unroll
        for (int rb = 0; rb < 2; ++rb) {
            f16x8 pa = *(const f16x8*)&sP[w][(rb * 16 + lr) * PP + lk];
#pragma unroll
            for (int nf = 0; nf < 4; ++nf)
                o[rb][nf] = __builtin_amdgcn_mfma_f32_16x16x32_f16(bv[nf], pa, o[rb][nf], 0, 0, 0);
        }
        __builtin_amdgcn_s_setprio(0);
    }

    // epilogue: lane q = q0 + w*32 + rb*16 + lr; d = 16nf + 4g + j (contiguous)
#pragma unroll
    for (int rb = 0; rb < 2; ++rb) {
        float lv = __shfl(o[rb][3][0], lr, 64);   // l from g=0 lane of this q
        int qr = q0 + w * 32 + rb * 16 + lr;
        if (qr < NTOK) {
            float inv = 1.f / lv;
            size_t rbse = ((size_t)b * NTOK + qr) * DIM;
#pragma unroll
            for (int nf = 0; nf < 3; ++nf) {
                ushort4 h4;
#pragma unroll
                for (int j = 0; j < 4; ++j)
                    ((ushort*)&h4)[j] = f2h(o[rb][nf][j] * inv);
                *(ushort4*)&aout[rbse + h * HD + nf * 16 + 4 * g] = h4;
            }
        }
    }
}

// ---------------- launch ------------------------------------------------------
extern "C" void kernel_launch(void* const* d_in, const int* in_sizes, int n_in,
                              void* d_out, int out_size, void* d_ws, size_t ws_size,
                              hipStream_t stream) {
    const float* x   = (const float*)d_in[0];
    const int*   pos = (const int*)d_in[1];
    const float* Wq  = (const float*)d_in[2];
    const float* Wp  = (const float*)d_in[3];
    const float* bp  = (const float*)d_in[4];
    float* out = (float*)d_out;

    ushort* ws     = (ushort*)d_ws;
    ushort* x_h    = ws;                                    // 6272*768 (later reused as vt)
    ushort* WqT    = x_h + (size_t)ROWS * DIM;              // 2304*768
    ushort* WpT    = WqT + (size_t)QKV_COLS * DIM;          // 768*768
    ushort* qkv_h  = WpT + (size_t)DIM * DIM;               // 6272*2304
    ushort* aout   = qkv_h + (size_t)ROWS * QKV_COLS;       // 6272*768
    ushort* vt     = x_h;   // alias: x_h dead after gemm1; 4*768*1568 == 6272*768

    cast_f32_f16<<<(ROWS * DIM / 4 + 255) / 256, 256, 0, stream>>>(x, x_h, ROWS * DIM / 4);
    transpose_cast<<<dim3(QKV_COLS / 32, DIM / 32), dim3(32, 8), 0, stream>>>(Wq, WqT, DIM, QKV_COLS);
    transpose_cast<<<dim3(DIM / 32, DIM / 32), dim3(32, 8), 0, stream>>>(Wp, WpT, DIM, DIM);

    // qkv = x @ W_qkv  (fp16 out)
    gemm_f16<128><<<dim3(QKV_COLS / 128, ROWS / 128), 256, 0, stream>>>(
        x_h, WqT, nullptr, qkv_h, nullptr, ROWS, QKV_COLS, DIM);

    // vt[b][c][n] = V^T (overwrites x_h, which is dead now)
    transpose_v<<<dim3(DIM / 32, NTOK / 32, BATCH), dim3(32, 8), 0, stream>>>(qkv_h, vt);

    rope_f16<<<(BATCH * NTOK * NHEADS * 3 + 255) / 256, 256, 0, stream>>>(qkv_h, pos);

    attn_mfma<<<dim3(BATCH * NHEADS, (NTOK + QBLK - 1) / QBLK), 256, 0, stream>>>(qkv_h, vt, aout);

    // out = aout @ WpT^T + b  (plain fp16, K=768, f32 out; BM=64 -> 588 blocks)
    gemm_f16<64><<<dim3(DIM / 128, ROWS / 64), 256, 0, stream>>>(
        aout, WpT, out, nullptr, bp, ROWS, DIM, DIM);
}

// Round 15
// 145.074 us; speedup vs baseline: 1.5004x; 1.0525x over previous
//
#include <hip/hip_runtime.h>
#include <hip/hip_bf16.h>
#include <math.h>

#define DIM 768
#define NHEADS 16
#define HD 48
#define NTOK 1568
#define BATCH 4
#define ROWS (BATCH * NTOK)     // 6272
#define QKV_COLS (3 * DIM)      // 2304

typedef __attribute__((ext_vector_type(8))) _Float16 f16x8;
typedef __attribute__((ext_vector_type(2))) __fp16 fp16v2;
typedef __attribute__((ext_vector_type(4))) float f32x4;

__device__ inline ushort f2h(float f) {
    union { _Float16 h; ushort u; } v; v.h = (_Float16)f; return v.u;
}
__device__ inline float h2f(ushort u) {
    union { _Float16 h; ushort u; } v; v.u = u; return (float)v.h;
}

// async global->LDS, 16B per lane; lds dest is wave-uniform base (+lane*16 by HW)
__device__ inline void gl16(const void* g, void* l) {
    __builtin_amdgcn_global_load_lds(
        (const __attribute__((address_space(1))) unsigned int*)g,
        (__attribute__((address_space(3))) unsigned int*)l, 16, 0, 0);
}

// ---------------- cast fp32 -> fp16 (vectorized) -----------------------------
__global__ void cast_f32_f16(const float* __restrict__ in, ushort* __restrict__ out, int n4) {
    int i = blockIdx.x * blockDim.x + threadIdx.x;
    if (i >= n4) return;
    float4 v = ((const float4*)in)[i];
    ushort4 o;
    o.x = f2h(v.x); o.y = f2h(v.y); o.z = f2h(v.z); o.w = f2h(v.w);
    ((ushort4*)out)[i] = o;
}

// ---------------- transpose-cast: in[R][C] f32 -> out[C][R] fp16 -------------
__global__ void transpose_cast(const float* __restrict__ in, ushort* __restrict__ out,
                               int R, int C) {
    __shared__ ushort tile[32][33];
    int tx = threadIdx.x, ty = threadIdx.y;
    int c0 = blockIdx.x * 32, r0 = blockIdx.y * 32;
#pragma unroll
    for (int k = 0; k < 4; ++k)
        tile[ty + 8 * k][tx] = f2h(in[(size_t)(r0 + ty + 8 * k) * C + c0 + tx]);
    __syncthreads();
#pragma unroll
    for (int k = 0; k < 4; ++k)
        out[(size_t)(c0 + ty + 8 * k) * R + r0 + tx] = tile[tx][ty + 8 * k];
}

// ---------------- fp16 MFMA GEMM: C[M][N] = A[M][K] * Bt[N][K]^T -------------
// Templated on BM (BN=128, BK=64). Double-buffered gload_lds staging, depth-1
// issue-early pipeline, ONE barrier per K-iter. SWAPPED mfma operands:
// acc = mfma(bg, af) -> lane holds m = lr (fixed), n = nb + g*4 + j
// (4 contiguous cols) -> vectorized C stores (8B fp16 pairs / 16B float4).
// If Vt != null, blocks with n0 >= 1536 write V^T to vt[b][c][tok] instead.
#define GBK 64

template <int BM>
__global__ __launch_bounds__(256) void gemm_f16(
    const ushort* __restrict__ A, const ushort* __restrict__ Bt,
    float* __restrict__ Cf, ushort* __restrict__ Cb, ushort* __restrict__ Vt,
    const float* __restrict__ bias, int M, int N, int K) {
    constexpr int MI = BM / 32;           // A m-frags per wave; A chunks/thread
    __shared__ ushort sA[2][BM * 64];
    __shared__ ushort sB[2][128 * 64];
    const int tid = threadIdx.x;
    const int wid = tid >> 6, lane = tid & 63;
    const int wm = wid >> 1, wn = wid & 1;          // 2x2 wave grid
    const int m0 = blockIdx.y * BM, n0 = blockIdx.x * 128;
    const int lr = lane & 15, g = lane >> 4;

    auto STAGE = [&](int buf, int k0) {
#pragma unroll
        for (int i = 0; i < MI; ++i) {      // A: BM*8 chunks
            int c = tid + 256 * i;
            int row = c >> 3;
            int ch = (c & 7) ^ (row & 7);   // source pre-swizzle
            gl16(&A[(size_t)(m0 + row) * K + k0 + ch * 8], &sA[buf][(c & ~63) * 8]);
        }
#pragma unroll
        for (int i = 0; i < 4; ++i) {       // B: 1024 chunks
            int c = tid + 256 * i;
            int row = c >> 3;
            int ch = (c & 7) ^ (row & 7);
            gl16(&Bt[(size_t)(n0 + row) * K + k0 + ch * 8], &sB[buf][(c & ~63) * 8]);
        }
    };

    f32x4 acc[MI][4] = {};
    const int NK = K / GBK;
    STAGE(0, 0);
    for (int t = 0; t < NK; ++t) {
        const int cur = t & 1;
        asm volatile("s_waitcnt vmcnt(0)" ::: "memory");
        __builtin_amdgcn_s_barrier();
        if (t + 1 < NK) STAGE(cur ^ 1, (t + 1) * GBK);
#pragma unroll
        for (int k2 = 0; k2 < GBK; k2 += 32) {
            f16x8 af[MI], bg[4];
#pragma unroll
            for (int f = 0; f < MI; ++f) {
                int ra = wm * (BM / 2) + f * 16 + lr;
                int ba = (ra * 128 + k2 * 2 + g * 16) ^ ((ra & 7) << 4);
                af[f] = *(const f16x8*)((const char*)sA[cur] + ba);
            }
#pragma unroll
            for (int f = 0; f < 4; ++f) {
                int rb = wn * 64 + f * 16 + lr;
                int bb = (rb * 128 + k2 * 2 + g * 16) ^ ((rb & 7) << 4);
                bg[f] = *(const f16x8*)((const char*)sB[cur] + bb);
            }
#pragma unroll
            for (int mi = 0; mi < MI; ++mi)
#pragma unroll
                for (int ni = 0; ni < 4; ++ni)
                    acc[mi][ni] = __builtin_amdgcn_mfma_f32_16x16x32_f16(
                        bg[ni], af[mi], acc[mi][ni], 0, 0, 0);
        }
    }
    // epilogue: lane m = m0 + wm*(BM/2) + mi*16 + lr; n = nb + g*4 + j contiguous
    const bool vpath = (Vt != nullptr) && (n0 >= 2 * DIM);
#pragma unroll
    for (int mi = 0; mi < MI; ++mi) {
        int m = m0 + wm * (BM / 2) + mi * 16 + lr;
#pragma unroll
        for (int ni = 0; ni < 4; ++ni) {
            int nb = n0 + wn * 64 + ni * 16 + g * 4;
            if (Cf) {
                float4 b4 = *(const float4*)&bias[nb];
                float4 o4;
                o4.x = acc[mi][ni][0] + b4.x;
                o4.y = acc[mi][ni][1] + b4.y;
                o4.z = acc[mi][ni][2] + b4.z;
                o4.w = acc[mi][ni][3] + b4.w;
                *(float4*)&Cf[(size_t)m * N + nb] = o4;
            } else if (vpath) {
                // vt[b][c][tok] = V^T; c = nb-1536+j, tok = m%NTOK
                int bb = m / NTOK, tok = m % NTOK;
#pragma unroll
                for (int j = 0; j < 4; ++j)
                    Vt[((size_t)bb * DIM + (nb - 2 * DIM + j)) * NTOK + tok] =
                        f2h(acc[mi][ni][j]);
            } else {
                union { fp16v2 h; uint u; } c0, c1;
                c0.h = __builtin_amdgcn_cvt_pkrtz(acc[mi][ni][0], acc[mi][ni][1]);
                c1.h = __builtin_amdgcn_cvt_pkrtz(acc[mi][ni][2], acc[mi][ni][3]);
                uint2 uu; uu.x = c0.u; uu.y = c1.u;
                *(uint2*)&Cb[(size_t)m * N + nb] = uu;
            }
        }
    }
}

// ---------------- RoPE 3D, vectorized: thread = (b,n,h,axis), 8 pairs --------
__global__ void rope_f16(ushort* __restrict__ qkv, const int* __restrict__ pos) {
    int idx = blockIdx.x * blockDim.x + threadIdx.x;
    const int total = BATCH * NTOK * NHEADS * 3;   // 301056
    if (idx >= total) return;
    int axis = idx % 3; int t = idx / 3;
    int h = t & 15; t >>= 4;
    int n = t % NTOK; int b = t / NTOK;

    float p = (float)pos[n * 3 + axis];
    size_t base = ((size_t)b * NTOK + n) * QKV_COLS + h * HD + axis * 16;

    ushort lo[8], hi[8], klo[8], khi[8];
    *(ushort4*)&lo[0] = *(ushort4*)&qkv[base];
    *(ushort4*)&lo[4] = *(ushort4*)&qkv[base + 4];
    *(ushort4*)&hi[0] = *(ushort4*)&qkv[base + 8];
    *(ushort4*)&hi[4] = *(ushort4*)&qkv[base + 12];
    *(ushort4*)&klo[0] = *(ushort4*)&qkv[base + DIM];
    *(ushort4*)&klo[4] = *(ushort4*)&qkv[base + DIM + 4];
    *(ushort4*)&khi[0] = *(ushort4*)&qkv[base + DIM + 8];
    *(ushort4*)&khi[4] = *(ushort4*)&qkv[base + DIM + 12];

    const float RINV = 0.31622776601683794f;   // 10000^(-1/8)
    float fj = 1.0f;
#pragma unroll
    for (int j = 0; j < 8; ++j) {
        float s, c; __sincosf(p * fj, &s, &c); fj *= RINV;
        float q1 = h2f(lo[j]), q2 = h2f(hi[j]);
        lo[j] = f2h(q1 * c - q2 * s);
        hi[j] = f2h(q2 * c + q1 * s);
        float k1 = h2f(klo[j]), k2 = h2f(khi[j]);
        klo[j] = f2h(k1 * c - k2 * s);
        khi[j] = f2h(k2 * c + k1 * s);
    }
    *(ushort4*)&qkv[base] = *(ushort4*)&lo[0];
    *(ushort4*)&qkv[base + 4] = *(ushort4*)&lo[4];
    *(ushort4*)&qkv[base + 8] = *(ushort4*)&hi[0];
    *(ushort4*)&qkv[base + 12] = *(ushort4*)&hi[4];
    *(ushort4*)&qkv[base + DIM] = *(ushort4*)&klo[0];
    *(ushort4*)&qkv[base + DIM + 4] = *(ushort4*)&klo[4];
    *(ushort4*)&qkv[base + DIM + 8] = *(ushort4*)&khi[0];
    *(ushort4*)&qkv[base + DIM + 12] = *(ushort4*)&khi[4];
}

// ---------------- MFMA flash attention (fp16) --------------------------------
// Grid: (64 bh, 13 q-tiles), bh%8 = XCD. QBLK=128 (wave owns 32 q-rows).
// TRIPLE-buffered K/V via global_load_lds, depth-2 pipeline, ONE barrier/tile.
// Fixed-offset exp2 softmax (M2=14); -M2 in MFMA C-init; l via ones-row.
#define QBLK 128
#define KVB 32
#define NT (NTOK / KVB)   // 49
#define PP 40             // sP pitch

__global__ __launch_bounds__(256) void attn_mfma(const ushort* __restrict__ qkv,
                                                 const ushort* __restrict__ vt,
                                                 ushort* __restrict__ aout) {
    __shared__ ushort sK3[3][KVB * 64];   // [32][64] linear, 12 KB
    __shared__ ushort sV3[3][64 * 32];    // rows 0..47 V^T, 48 = ones; 12 KB
    __shared__ ushort sP[4][32 * PP];     // 10 KB
    const int tid = threadIdx.x, w = tid >> 6, lane = tid & 63;
    const int b = blockIdx.x >> 4, h = blockIdx.x & 15;
    const int q0 = blockIdx.y * QBLK;
    const size_t bbase = (size_t)b * NTOK * QKV_COLS;
    const size_t vbase = ((size_t)b * DIM + h * HD) * NTOK;
    const int lr = lane & 15, g = lane >> 4, lk = g << 3;
    const float qs = 0.14433756729740643f * 1.4426950408889634f;  // 1/sqrt(48)*log2e
    const float M2 = 14.0f;   // fixed exp2-domain offset (folded into C-init)

    // ones-row for l-accumulation (row 48 of all 3 V buffers)
    if (tid < 32) {
        sV3[0][48 * 32 + tid] = 0x3C00;   // 1.0 fp16
        sV3[1][48 * 32 + tid] = 0x3C00;
        sV3[2][48 * 32 + tid] = 0x3C00;
    }
    asm volatile("s_waitcnt lgkmcnt(0)" ::: "memory");

    // Q direct to registers, scaled by qs; cols >= 48 zero (nulls K garbage)
    f16x8 aq[2][2];
#pragma unroll
    for (int rb = 0; rb < 2; ++rb) {
        int qr = q0 + w * 32 + rb * 16 + lr;
        if (qr >= NTOK) qr = NTOK - 1;
        const ushort* qp = &qkv[bbase + (size_t)qr * QKV_COLS + h * HD];
        ushort r0[8], r1[8];
        *(ushort4*)&r0[0] = *(const ushort4*)&qp[lk];
        *(ushort4*)&r0[4] = *(const ushort4*)&qp[lk + 4];
        if (g < 2) {
            *(ushort4*)&r1[0] = *(const ushort4*)&qp[32 + lk];
            *(ushort4*)&r1[4] = *(const ushort4*)&qp[32 + lk + 4];
        } else {
#pragma unroll
            for (int e = 0; e < 8; ++e) r1[e] = 0;
        }
        f16x8 a0, a1;
#pragma unroll
        for (int e = 0; e < 8; ++e) {
            a0[e] = (_Float16)(h2f(r0[e]) * qs);
            a1[e] = (_Float16)(h2f(r1[e]) * qs);
        }
        aq[rb][0] = a0; aq[rb][1] = a1;
    }

    // stage K (256 chunks) + V (192 chunks) for tile kv0 into buffer buf
    auto STAGE = [&](int buf, int kv0) {
        {   // K: chunk c = tid; row = c>>3; source chunk swizzled
            int c = tid, row = c >> 3;
            int ch = (c & 7) ^ (row & 7);
            gl16(&qkv[bbase + (size_t)(kv0 + row) * QKV_COLS + DIM + h * HD + ch * 8],
                 &sK3[buf][(c & ~63) * 8]);
        }
        if (lane < 48) {   // V: wave w stages chunks w*48..w*48+47 (rows 0..47)
            int c = w * 48 + lane, d = c >> 2;
            int cc = (c & 3) ^ ((d >> 1) & 3);
            gl16(&vt[vbase + (size_t)d * NTOK + kv0 + cc * 8],
                 &sV3[buf][w * 384]);
        }
    };

    f32x4 o[2][4] = {};   // per rb: d 0..47 in [0..2]; [3][0] (g=0) = l

    STAGE(0, 0);
    STAGE(1, KVB);
    for (int t = 0; t < NT; ++t) {
        const int cur = t % 3;
        if (t + 1 < NT) asm volatile("s_waitcnt vmcnt(2)" ::: "memory");
        else            asm volatile("s_waitcnt vmcnt(0)" ::: "memory");
        __builtin_amdgcn_s_barrier();
        if (t + 2 < NT) STAGE((t + 2) % 3, (t + 2) * KVB);

        // S^T = K Q^T - M2: lane: q = rb*16+lr, keys = f*16 + 4g + j
        f16x8 bk[2][2];
#pragma unroll
        for (int f = 0; f < 2; ++f)
#pragma unroll
            for (int ks = 0; ks < 2; ++ks) {
                int row = f * 16 + lr;
                int byt = (row * 128 + ks * 64 + g * 16) ^ ((lr & 7) << 4);
                bk[f][ks] = *(const f16x8*)((const char*)sK3[cur] + byt);
            }
        f32x4 sacc[2][2] = {{{-M2, -M2, -M2, -M2}, {-M2, -M2, -M2, -M2}},
                            {{-M2, -M2, -M2, -M2}, {-M2, -M2, -M2, -M2}}};
        __builtin_amdgcn_s_setprio(1);
#pragma unroll
        for (int rb = 0; rb < 2; ++rb)
#pragma unroll
            for (int f = 0; f < 2; ++f) {
                sacc[rb][f] = __builtin_amdgcn_mfma_f32_16x16x32_f16(bk[f][0], aq[rb][0], sacc[rb][f], 0, 0, 0);
                sacc[rb][f] = __builtin_amdgcn_mfma_f32_16x16x32_f16(bk[f][1], aq[rb][1], sacc[rb][f], 0, 0, 0);
            }
        __builtin_amdgcn_s_setprio(0);

        // p = 2^(s2-M2); pack adjacent-key pairs (cvt_pkrtz) -> b64 stores
#pragma unroll
        for (int rb = 0; rb < 2; ++rb)
#pragma unroll
            for (int f = 0; f < 2; ++f) {
                float p[4];
#pragma unroll
                for (int j = 0; j < 4; ++j) {
                    float pv;
                    asm("v_exp_f32 %0, %1" : "=v"(pv) : "v"(sacc[rb][f][j]));
                    p[j] = pv;
                }
                union { fp16v2 h; uint u; } c0, c1;
                c0.h = __builtin_amdgcn_cvt_pkrtz(p[0], p[1]);
                c1.h = __builtin_amdgcn_cvt_pkrtz(p[2], p[3]);
                uint2 uu; uu.x = c0.u; uu.y = c1.u;
                *(uint2*)&sP[w][(rb * 16 + lr) * PP + f * 16 + 4 * g] = uu;
            }

        // PV (swapped): o^T = mfma(V^T, P): lane: q = lr, d = 16nf + 4g + j
        // nf=3 row 48 = ones -> accumulates l into o[rb][3] (g=0,j=0)
        f16x8 bv[4];
#pragma unroll
        for (int nf = 0; nf < 4; ++nf) {
            int row = nf * 16 + lr;
            int byt = (row * 64 + g * 16) ^ (((lr >> 1) & 3) << 4);
            bv[nf] = *(const f16x8*)((const char*)sV3[cur] + byt);
        }
        __builtin_amdgcn_s_setprio(1);
#pragma unroll
        for (int rb = 0; rb < 2; ++rb) {
            f16x8 pa = *(const f16x8*)&sP[w][(rb * 16 + lr) * PP + lk];
#pragma unroll
            for (int nf = 0; nf < 4; ++nf)
                o[rb][nf] = __builtin_amdgcn_mfma_f32_16x16x32_f16(bv[nf], pa, o[rb][nf], 0, 0, 0);
        }
        __builtin_amdgcn_s_setprio(0);
    }

    // epilogue: lane q = q0 + w*32 + rb*16 + lr; d = 16nf + 4g + j (contiguous)
#pragma unroll
    for (int rb = 0; rb < 2; ++rb) {
        float lv = __shfl(o[rb][3][0], lr, 64);   // l from g=0 lane of this q
        int qr = q0 + w * 32 + rb * 16 + lr;
        if (qr < NTOK) {
            float inv = 1.f / lv;
            size_t rbse = ((size_t)b * NTOK + qr) * DIM;
#pragma unroll
            for (int nf = 0; nf < 3; ++nf) {
                ushort4 h4;
#pragma unroll
                for (int j = 0; j < 4; ++j)
                    ((ushort*)&h4)[j] = f2h(o[rb][nf][j] * inv);
                *(ushort4*)&aout[rbse + h * HD + nf * 16 + 4 * g] = h4;
            }
        }
    }
}

// ---------------- launch ------------------------------------------------------
extern "C" void kernel_launch(void* const* d_in, const int* in_sizes, int n_in,
                              void* d_out, int out_size, void* d_ws, size_t ws_size,
                              hipStream_t stream) {
    const float* x   = (const float*)d_in[0];
    const int*   pos = (const int*)d_in[1];
    const float* Wq  = (const float*)d_in[2];
    const float* Wp  = (const float*)d_in[3];
    const float* bp  = (const float*)d_in[4];
    float* out = (float*)d_out;

    ushort* ws     = (ushort*)d_ws;
    ushort* x_h    = ws;                                    // 6272*768
    ushort* WqT    = x_h + (size_t)ROWS * DIM;              // 2304*768
    ushort* WpT    = WqT + (size_t)QKV_COLS * DIM;          // 768*768
    ushort* qkv_h  = WpT + (size_t)DIM * DIM;               // 6272*2304 (V third unused)
    ushort* aout   = qkv_h + (size_t)ROWS * QKV_COLS;       // 6272*768
    ushort* vt     = aout + (size_t)ROWS * DIM;             // 4*768*1568 (separate!)

    cast_f32_f16<<<(ROWS * DIM / 4 + 255) / 256, 256, 0, stream>>>(x, x_h, ROWS * DIM / 4);
    transpose_cast<<<dim3(QKV_COLS / 32, DIM / 32), dim3(32, 8), 0, stream>>>(Wq, WqT, DIM, QKV_COLS);
    transpose_cast<<<dim3(DIM / 32, DIM / 32), dim3(32, 8), 0, stream>>>(Wp, WpT, DIM, DIM);

    // qkv = x @ W_qkv; q/k -> qkv_h, v -> vt (transposed in epilogue)
    gemm_f16<128><<<dim3(QKV_COLS / 128, ROWS / 128), 256, 0, stream>>>(
        x_h, WqT, nullptr, qkv_h, vt, nullptr, ROWS, QKV_COLS, DIM);

    rope_f16<<<(BATCH * NTOK * NHEADS * 3 + 255) / 256, 256, 0, stream>>>(qkv_h, pos);

    attn_mfma<<<dim3(BATCH * NHEADS, (NTOK + QBLK - 1) / QBLK), 256, 0, stream>>>(qkv_h, vt, aout);

    // out = aout @ WpT^T + b  (K=768, f32 out; BM=64 -> 588 blocks)
    gemm_f16<64><<<dim3(DIM / 128, ROWS / 64), 256, 0, stream>>>(
        aout, WpT, out, nullptr, nullptr, bp, ROWS, DIM, DIM);
}